// Round 10
// baseline (194.991 us; speedup 1.0000x reference)
//
#include <hip/hip_runtime.h>
#include <hip/hip_bf16.h>

#define BATCH 32
#define CCH   1536
#define ACH   128
#define TLEN  1000
#define TPAD  1024
#define NCB   (CCH / 64)      // 24 channel blocks in xt layout
#define XTB   (TPAD * 64)     // elements per (b, cblk) panel = 65536
#define NCHK  16              // pooling chunks (64 t each) in fused path
#define TSPLIT 4
#define TCHUNK 256
#define TSA   2               // kA t-split
#define EPSV  1e-5f
#define NINF  -3.0e38f
#define LOG2E 1.4426950408889634f
#define RTHR  11.5f

typedef __attribute__((ext_vector_type(8))) short bf16x8;
typedef __attribute__((ext_vector_type(4))) float f32x4;

__device__ __forceinline__ unsigned short f2bf(float f) {
    union { float f; unsigned u; } v; v.f = f;
    unsigned r = v.u + 0x7fffu + ((v.u >> 16) & 1u);
    return (unsigned short)(r >> 16);
}
__device__ __forceinline__ float bf2f(unsigned short u) {
    union { unsigned u; float f; } v; v.u = ((unsigned)u) << 16;
    return v.f;
}

// ---------------- Kernel A: cast/transpose x -> xt blocked [b][cblk][t][64c] bf16,
// stats accumulated in the LDS READ phase (loads have no same-iteration consumer).
__global__ __launch_bounds__(512) void kA(const float* __restrict__ x,
                                          unsigned short* __restrict__ xt,
                                          float* __restrict__ st1,
                                          float* __restrict__ st2) {
    int b = blockIdx.y, cblk = blockIdx.x, ts = blockIdx.z;
    int cb = cblk * 64;
    int tbase = ts * (TPAD / TSA);             // 0 or 512
    int tid = threadIdx.x;
    int row = tid >> 3, l8 = tid & 7;          // 64 rows (channels), 8 lanes/row
    __shared__ float tile[2][64][65];          // [buf][t][c]
    __shared__ float red1[8][64], red2[8][64]; // per-wave channel partials
    const float* xr = x + ((size_t)(b * CCH + cb + row)) * TLEN + tbase;
    unsigned short* xtp = xt + ((size_t)(b * NCB + cblk)) * XTB + (size_t)tbase * 64;

    float4 rA[2];
    float cs1[8], cs2[8];
    #pragma unroll
    for (int j = 0; j < 8; ++j) { cs1[j] = 0.f; cs2[j] = 0.f; }

    auto loadTile = [&](int it) {
        #pragma unroll
        for (int p = 0; p < 2; ++p) {
            int tf = it * 64 + p * 32 + l8 * 4;
            float4 vv = make_float4(0.f, 0.f, 0.f, 0.f);
            if (tbase + tf < TLEN) vv = *reinterpret_cast<const float4*>(xr + tf);
            rA[p] = vv;                      // no other consumer here: true prefetch
        }
    };
    auto writeTile = [&](int buf) {
        #pragma unroll
        for (int p = 0; p < 2; ++p) {
            int tl = p * 32 + l8 * 4;
            tile[buf][tl + 0][row] = rA[p].x;
            tile[buf][tl + 1][row] = rA[p].y;
            tile[buf][tl + 2][row] = rA[p].z;
            tile[buf][tl + 3][row] = rA[p].w;
        }
    };
    auto readStore = [&](int buf, int it) {
        int tl = tid >> 3;             // 64 t-rows
        int c8 = (tid & 7) * 8;        // 8 channels; contiguous 128B per t-row
        float v[8];
        #pragma unroll
        for (int j = 0; j < 8; ++j) {
            v[j] = tile[buf][tl][c8 + j];
            cs1[j] += v[j];
            cs2[j] += v[j] * v[j];
        }
        unsigned o[4];
        #pragma unroll
        for (int j = 0; j < 4; ++j)
            o[j] = (unsigned)f2bf(v[2 * j]) | ((unsigned)f2bf(v[2 * j + 1]) << 16);
        uint4 u; u.x = o[0]; u.y = o[1]; u.z = o[2]; u.w = o[3];
        *reinterpret_cast<uint4*>(xtp + (size_t)(it * 64 + tl) * 64 + c8) = u;
    };

    const int NIT = (TPAD / TSA) / 64;   // 8
    loadTile(0);
    writeTile(0);
    loadTile(1);
    __syncthreads();
    for (int it = 0; it < NIT; ++it) {
        int buf = it & 1;
        if (it < NIT - 1) writeTile(buf ^ 1);   // consumes loads issued 2 iters ago
        if (it < NIT - 2) loadTile(it + 2);     // pure issue, no wait
        readStore(buf, it);                     // LDS reads + stats + streaming store
        __syncthreads();
    }

    #pragma unroll
    for (int j = 0; j < 8; ++j) {
        #pragma unroll
        for (int d = 8; d < 64; d <<= 1) {
            cs1[j] += __shfl_xor(cs1[j], d);
            cs2[j] += __shfl_xor(cs2[j], d);
        }
    }
    int wv = tid >> 6, lane = tid & 63;
    if (lane < 8) {
        #pragma unroll
        for (int j = 0; j < 8; ++j) {
            red1[wv][lane * 8 + j] = cs1[j];
            red2[wv][lane * 8 + j] = cs2[j];
        }
    }
    __syncthreads();
    if (tid < 64) {
        float s1 = 0.f, s2 = 0.f;
        #pragma unroll
        for (int w = 0; w < 8; ++w) { s1 += red1[w][tid]; s2 += red2[w][tid]; }
        st1[((size_t)ts * BATCH + b) * CCH + cb + tid] = s1;
        st2[((size_t)ts * BATCH + b) * CCH + cb + tid] = s2;
    }
}

// Stats-only fallback (writes st-format partials; second slice zeroed)
__global__ __launch_bounds__(256) void kA2(const float* __restrict__ x,
                                           float* __restrict__ st1,
                                           float* __restrict__ st2) {
    int b = blockIdx.y, cb = blockIdx.x * 32;
    int tid = threadIdx.x;
    int row = tid >> 3, l8 = tid & 7;
    const float* xr = x + ((size_t)(b * CCH + cb + row)) * TLEN;
    float s1 = 0.f, s2 = 0.f;
    for (int tf = l8 * 4; tf < TLEN; tf += 32) {
        float4 vv = *reinterpret_cast<const float4*>(xr + tf);
        s1 += vv.x + vv.y + vv.z + vv.w;
        s2 += vv.x * vv.x + vv.y * vv.y + vv.z * vv.z + vv.w * vv.w;
    }
    #pragma unroll
    for (int d = 1; d < 8; d <<= 1) { s1 += __shfl_xor(s1, d); s2 += __shfl_xor(s2, d); }
    if (l8 == 0) {
        int idx = b * CCH + cb + row;
        st1[idx] = s1;
        st2[idx] = s2;
        st1[(size_t)BATCH * CCH + idx] = 0.f;
        st2[(size_t)BATCH * CCH + idx] = 0.f;
    }
}

// ---------------- BW: fused prep — w1 x-part cast (first 768 blocks) + BN1-folded w2 (next 384)
__global__ __launch_bounds__(256) void kBW(const float* __restrict__ w1,
                                           unsigned short* __restrict__ w1x,
                                           const float* __restrict__ w2,
                                           const float* __restrict__ b2,
                                           const float* __restrict__ g1,
                                           const float* __restrict__ be1,
                                           const float* __restrict__ rm1,
                                           const float* __restrict__ rv1,
                                           unsigned short* __restrict__ w2e,
                                           float* __restrict__ b2e) {
    int bx = blockIdx.x;
    const int NB1 = (ACH * CCH) / 256;   // 768
    if (bx < NB1) {
        int e = bx * 256 + threadIdx.x;
        int a = e / CCH, c = e - a * CCH;
        w1x[e] = f2bf(w1[(size_t)a * (3 * CCH) + c]);
    } else {
        int c = (bx - NB1) * 4 + (threadIdx.x >> 6);   // 4 channels/block, 1 wave each
        int l = threadIdx.x & 63;
        float acc = 0.f;
        #pragma unroll
        for (int p = 0; p < 2; ++p) {
            int a = p * 64 + l;
            float s1 = g1[a] * rsqrtf(rv1[a] + EPSV);
            float w = w2[(size_t)c * ACH + a];
            w2e[(size_t)c * ACH + a] = f2bf(w * s1 * LOG2E);   // logits in log2 units
            acc += w * (be1[a] - s1 * rm1[a]);
        }
        #pragma unroll
        for (int d = 1; d < 64; d <<= 1) acc += __shfl_xor(acc, d);
        if (l == 0) b2e[c] = (b2[c] + acc) * LOG2E;
    }
}

// ---------------- B2n: hbias[b][a] = b1[a] + sum_c w1m*mean + w1s*std
__global__ __launch_bounds__(64) void kB2n(const float* __restrict__ w1,
                                           const float* __restrict__ b1,
                                           const float* __restrict__ st1,
                                           const float* __restrict__ st2,
                                           float* __restrict__ hbias) {
    int a = blockIdx.x, b = blockIdx.y, l = threadIdx.x;
    const float* wr = w1 + (size_t)a * 3 * CCH;
    const float* p1 = st1 + (size_t)b * CCH;
    const float* p2 = st2 + (size_t)b * CCH;
    const size_t half = (size_t)BATCH * CCH;
    float acc = 0.f;
    const float invT = 1.f / (float)TLEN;
    const float invT1 = 1.f / (float)(TLEN - 1);
    for (int k = l; k < CCH; k += 64) {
        float s1 = p1[k] + p1[half + k];
        float s2 = p2[k] + p2[half + k];
        float mean = s1 * invT;
        float var = (s2 - s1 * s1 * invT) * invT1;
        float stdv = sqrtf(var + EPSV);
        acc += wr[CCH + k] * mean + wr[2 * CCH + k] * stdv;
    }
    #pragma unroll
    for (int d = 1; d < 64; d <<= 1) acc += __shfl_xor(acc, d);
    if (l == 0) hbias[b * ACH + a] = acc + b1[a];
}

// ---------------- CD: FUSED GEMM1 + GEMM2 + softmax pooling partials.
// Block (t-chunk of 64, b). Phase 1: h[128a][64t] via LDS-staged MFMA (kC3 body),
// epilogue -> h to LDS (swizzled). Phase 2: 12 c-strips of 128: logits = w2e @ h,
// closed softmax over 64 t + weighted stats from xs (re-staged L2-hot xt slices).
__global__ __launch_bounds__(512) void kCD(const unsigned short* __restrict__ xt,
                                           const unsigned short* __restrict__ w1x,
                                           const float* __restrict__ hbias,
                                           const unsigned short* __restrict__ w2e,
                                           const float* __restrict__ b2e,
                                           float4* __restrict__ part) {
    int b = blockIdx.y;
    int t0 = blockIdx.x * 64;
    int tid = threadIdx.x;
    int wv = tid >> 6, l = tid & 63, g = l >> 4, r = l & 15;
    int a0 = (wv & 3) * 32;
    int tw = (wv >> 2) * 32;

    __shared__ uint4 As[2][1024];   // [128a][64c] bf16, swizzled 16B chunks
    __shared__ uint4 Bs[2][512];    // [64t][64c]  bf16, swizzled
    __shared__ uint2 hsl[2048];     // [64t][128a] bf16, chunk-swizzled (16KB)
    __shared__ uint2 xs[2048];      // [64t][128c] bf16, granule-swizzled (16KB)

    const unsigned short* bG = xt + (size_t)b * NCB * XTB;   // panel base for batch b

    // ---- Phase 1: GEMM1 (identical structure to kC3) ----
    int qa0 = tid, qa1 = tid + 512, qb = tid;
    int wa0 = qa0 ^ ((qa0 >> 3) & 7), wa1 = qa1 ^ ((qa1 >> 3) & 7), wb = qb ^ ((qb >> 3) & 7);
    int arow0 = qa0 >> 3, arow1 = qa1 >> 3, acol = (qa0 & 7) * 8;
    int brow = qb >> 3, bcol = (qb & 7) * 8;

    As[0][wa0] = *reinterpret_cast<const uint4*>(w1x + (size_t)arow0 * CCH + acol);
    As[0][wa1] = *reinterpret_cast<const uint4*>(w1x + (size_t)arow1 * CCH + acol);
    Bs[0][wb]  = *reinterpret_cast<const uint4*>(bG + (size_t)(t0 + brow) * 64 + bcol);
    __syncthreads();

    f32x4 acc[2][2];
    #pragma unroll
    for (int i = 0; i < 2; ++i)
        #pragma unroll
        for (int j = 0; j < 2; ++j) acc[i][j] = f32x4{0.f, 0.f, 0.f, 0.f};

    for (int ks = 0; ks < CCH / 64; ++ks) {
        int buf = ks & 1;
        uint4 na0, na1, nb;
        if (ks < CCH / 64 - 1) {
            int cofs = (ks + 1) * 64;
            na0 = *reinterpret_cast<const uint4*>(w1x + (size_t)arow0 * CCH + cofs + acol);
            na1 = *reinterpret_cast<const uint4*>(w1x + (size_t)arow1 * CCH + cofs + acol);
            nb  = *reinterpret_cast<const uint4*>(bG + (size_t)(ks + 1) * XTB + (size_t)(t0 + brow) * 64 + bcol);
        }
        bf16x8 Af[2][2], Bf[2][2];
        #pragma unroll
        for (int at = 0; at < 2; ++at) {
            int row = a0 + 16 * at + r;
            #pragma unroll
            for (int kk = 0; kk < 2; ++kk) {
                int ch = (row * 8 + kk * 4 + g) ^ (row & 7);
                Af[at][kk] = *reinterpret_cast<const bf16x8*>(&As[buf][ch]);
            }
        }
        #pragma unroll
        for (int tt = 0; tt < 2; ++tt) {
            int row = tw + 16 * tt + r;
            #pragma unroll
            for (int kk = 0; kk < 2; ++kk) {
                int ch = (row * 8 + kk * 4 + g) ^ (row & 7);
                Bf[tt][kk] = *reinterpret_cast<const bf16x8*>(&Bs[buf][ch]);
            }
        }
        #pragma unroll
        for (int kk = 0; kk < 2; ++kk)
            #pragma unroll
            for (int at = 0; at < 2; ++at)
                #pragma unroll
                for (int tt = 0; tt < 2; ++tt)
                    acc[at][tt] = __builtin_amdgcn_mfma_f32_16x16x32_bf16(Af[at][kk], Bf[tt][kk], acc[at][tt], 0, 0, 0);
        if (ks < CCH / 64 - 1) {
            As[buf ^ 1][wa0] = na0;
            As[buf ^ 1][wa1] = na1;
            Bs[buf ^ 1][wb]  = nb;
        }
        __syncthreads();
    }

    // ---- Phase 1 epilogue: h -> LDS (swizzled), + issue xs loads for strip 0 ----
    int xtl_ = tid >> 3, xcw = tid & 7;
    auto xsrc = [&](int s, int p) {
        return reinterpret_cast<const uint4*>(bG + (size_t)(2 * s + p) * XTB
                                              + (size_t)(t0 + xtl_) * 64 + xcw * 8);
    };
    uint4 px0 = *xsrc(0, 0);
    uint4 px1 = *xsrc(0, 1);

    {
        f32x4 hb0 = *reinterpret_cast<const f32x4*>(hbias + b * ACH + a0 + 4 * g);
        f32x4 hb1 = *reinterpret_cast<const f32x4*>(hbias + b * ACH + a0 + 16 + 4 * g);
        #pragma unroll
        for (int at = 0; at < 2; ++at) {
            f32x4 hb = at ? hb1 : hb0;
            #pragma unroll
            for (int tt = 0; tt < 2; ++tt) {
                int t = tw + 16 * tt + r;
                float v0 = acc[at][tt][0] + hb[0]; v0 = v0 > 0.f ? v0 : 0.f;
                float v1 = acc[at][tt][1] + hb[1]; v1 = v1 > 0.f ? v1 : 0.f;
                float v2 = acc[at][tt][2] + hb[2]; v2 = v2 > 0.f ? v2 : 0.f;
                float v3 = acc[at][tt][3] + hb[3]; v3 = v3 > 0.f ? v3 : 0.f;
                uint2 u;
                u.x = (unsigned)f2bf(v0) | ((unsigned)f2bf(v1) << 16);
                u.y = (unsigned)f2bf(v2) | ((unsigned)f2bf(v3) << 16);
                int ccol = 4 * (wv & 3) + 2 * at + (g >> 1);
                int ch = (t * 16 + ccol) ^ (t & 7);
                hsl[ch * 2 + (g & 1)] = u;
            }
        }
        // stage xs strip 0
        int g0 = ((xtl_ * 32 + 2 * xcw) ^ ((xtl_ & 7) << 1));
        int g1i = ((xtl_ * 32 + 16 + 2 * xcw) ^ ((xtl_ & 7) << 1));
        *reinterpret_cast<uint4*>(&xs[g0]) = px0;
        *reinterpret_cast<uint4*>(&xs[g1i]) = px1;
    }
    __syncthreads();

    // ---- Phase 2: 12 c-strips of 128 ----
    for (int s = 0; s < CCH / 128; ++s) {
        uint4 nx0, nx1;
        if (s < CCH / 128 - 1) {
            nx0 = *xsrc(s + 1, 0);
            nx1 = *xsrc(s + 1, 1);
        }
        int c0s = s * 128;
        int crow = c0s + 16 * wv + r;
        bf16x8 Wf[4];
        #pragma unroll
        for (int kk = 0; kk < 4; ++kk)
            Wf[kk] = *reinterpret_cast<const bf16x8*>(w2e + (size_t)crow * ACH + 32 * kk + 8 * g);
        f32x4 acc2[4];
        #pragma unroll
        for (int tt = 0; tt < 4; ++tt) acc2[tt] = f32x4{0.f, 0.f, 0.f, 0.f};
        #pragma unroll
        for (int tt = 0; tt < 4; ++tt) {
            int t = 16 * tt + r;
            #pragma unroll
            for (int kk = 0; kk < 4; ++kk) {
                int ch = (t * 16 + kk * 4 + g) ^ (t & 7);
                bf16x8 Hf = *reinterpret_cast<const bf16x8*>(&hsl[ch * 2]);
                acc2[tt] = __builtin_amdgcn_mfma_f32_16x16x32_bf16(Wf[kk], Hf, acc2[tt], 0, 0, 0);
            }
        }
        f32x4 b2v = *reinterpret_cast<const f32x4*>(b2e + c0s + 16 * wv + 4 * g);
        uint2 xu[4];
        #pragma unroll
        for (int tt = 0; tt < 4; ++tt)
            xu[tt] = xs[(((16 * tt + r) << 5) | (4 * wv + g)) ^ ((r & 7) << 1)];

        #pragma unroll
        for (int i = 0; i < 4; ++i) {
            float v[4];
            #pragma unroll
            for (int tt = 0; tt < 4; ++tt) {
                int t = t0 + 16 * tt + r;
                v[tt] = (t < TLEN) ? (acc2[tt][i] + b2v[i]) : NINF;
            }
            float mm = fmaxf(fmaxf(v[0], v[1]), fmaxf(v[2], v[3]));
            #pragma unroll
            for (int d = 1; d < 16; d <<= 1) mm = fmaxf(mm, __shfl_xor(mm, d));
            float ss = 0.f, sx = 0.f, sxx = 0.f;
            #pragma unroll
            for (int tt = 0; tt < 4; ++tt) {
                float e = exp2f(v[tt] - mm);
                unsigned w = (i & 2) ? xu[tt].y : xu[tt].x;
                float xv = bf2f((unsigned short)((i & 1) ? (w >> 16) : (w & 0xffff)));
                float xe = xv * e;
                ss += e; sx += xe; sxx += xv * xe;
            }
            #pragma unroll
            for (int d = 1; d < 16; d <<= 1) {
                ss += __shfl_xor(ss, d);
                sx += __shfl_xor(sx, d);
                sxx += __shfl_xor(sxx, d);
            }
            if (r == 0) {
                int c = c0s + 16 * wv + 4 * g + i;
                float4 p; p.x = mm; p.y = ss; p.z = sx; p.w = sxx;
                part[((size_t)(b * NCHK + blockIdx.x)) * CCH + c] = p;
            }
        }

        if (s < CCH / 128 - 1) {
            __syncthreads();   // all waves done reading xs
            int g0 = ((xtl_ * 32 + 2 * xcw) ^ ((xtl_ & 7) << 1));
            int g1i = ((xtl_ * 32 + 16 + 2 * xcw) ^ ((xtl_ & 7) << 1));
            *reinterpret_cast<uint4*>(&xs[g0]) = nx0;
            *reinterpret_cast<uint4*>(&xs[g1i]) = nx1;
            __syncthreads();   // xs ready for strip s+1
        }
    }
}

// Fallback GEMM1: gather x fp32 directly (slow but correct), used if no room for xt
__global__ __launch_bounds__(256) void kC2(const float* __restrict__ x,
                                           const unsigned short* __restrict__ w1x,
                                           const float* __restrict__ hbias,
                                           unsigned short* __restrict__ h) {
    int b = blockIdx.y;
    int t0 = blockIdx.x * 32;
    int tid = threadIdx.x;
    int wv = tid >> 6, l = tid & 63, g = l >> 4, r = l & 15;
    const unsigned short* aptr = w1x + (size_t)(32 * wv + r) * CCH + 8 * g;
    f32x4 acc[2][2];
    #pragma unroll
    for (int i = 0; i < 2; ++i)
        #pragma unroll
        for (int j = 0; j < 2; ++j) acc[i][j] = f32x4{0.f, 0.f, 0.f, 0.f};
    for (int kk = 0; kk < CCH / 32; ++kk) {
        bf16x8 Af[2], Bf[2];
        #pragma unroll
        for (int at = 0; at < 2; ++at)
            Af[at] = *reinterpret_cast<const bf16x8*>(aptr + (size_t)(16 * at) * CCH + 32 * kk);
        #pragma unroll
        for (int tt = 0; tt < 2; ++tt) {
            int t = t0 + 16 * tt + r;
            unsigned short tmp[8];
            #pragma unroll
            for (int j = 0; j < 8; ++j) {
                float xv = 0.f;
                if (t < TLEN) xv = x[((size_t)(b * CCH + 32 * kk + 8 * g + j)) * TLEN + t];
                tmp[j] = f2bf(xv);
            }
            Bf[tt] = *reinterpret_cast<const bf16x8*>(tmp);
        }
        #pragma unroll
        for (int at = 0; at < 2; ++at)
            #pragma unroll
            for (int tt = 0; tt < 2; ++tt)
                acc[at][tt] = __builtin_amdgcn_mfma_f32_16x16x32_bf16(Af[at], Bf[tt], acc[at][tt], 0, 0, 0);
    }
    #pragma unroll
    for (int at = 0; at < 2; ++at) {
        f32x4 hb = *reinterpret_cast<const f32x4*>(hbias + b * ACH + 32 * wv + 16 * at + 4 * g);
        #pragma unroll
        for (int tt = 0; tt < 2; ++tt) {
            int t = t0 + 16 * tt + r;
            float v0 = acc[at][tt][0] + hb[0]; v0 = v0 > 0.f ? v0 : 0.f;
            float v1 = acc[at][tt][1] + hb[1]; v1 = v1 > 0.f ? v1 : 0.f;
            float v2 = acc[at][tt][2] + hb[2]; v2 = v2 > 0.f ? v2 : 0.f;
            float v3 = acc[at][tt][3] + hb[3]; v3 = v3 > 0.f ? v3 : 0.f;
            uint2 u;
            u.x = (unsigned)f2bf(v0) | ((unsigned)f2bf(v1) << 16);
            u.y = (unsigned)f2bf(v2) | ((unsigned)f2bf(v3) << 16);
            *reinterpret_cast<uint2*>(h + ((size_t)(b * TPAD + t)) * ACH + 32 * wv + 16 * at + 4 * g) = u;
        }
    }
}

// Fallback D (reads fp32 x via LDS staging) — used only when xt doesn't fit
__global__ __launch_bounds__(256) void kD1(const float* __restrict__ x,
                                           const unsigned short* __restrict__ h,
                                           const unsigned short* __restrict__ w2e,
                                           const float* __restrict__ b2e,
                                           float4* __restrict__ part) {
    int b = blockIdx.y, ts = blockIdx.z;
    int cblk = blockIdx.x * 64;
    int tid = threadIdx.x;
    int wv = tid >> 6, l = tid & 63, g = l >> 4, r = l & 15;
    int c0 = cblk + 16 * wv;
    int t0 = ts * TCHUNK;
    __shared__ float xsf[2][64][36];

    bf16x8 W[4];
    #pragma unroll
    for (int kk = 0; kk < 4; ++kk)
        W[kk] = *reinterpret_cast<const bf16x8*>(w2e + (size_t)(c0 + r) * ACH + 32 * kk + 8 * g);
    f32x4 b2v = *reinterpret_cast<const f32x4*>(b2e + c0 + 4 * g);

    int sc_ = tid >> 2;
    int st_ = (tid & 3) * 8;
    const float* xrow = x + ((size_t)(b * CCH + cblk + sc_)) * TLEN;
    const unsigned short* hb = h + (size_t)(b * TPAD) * ACH + 8 * g;

    auto stage = [&](int buf, int tc) {
        int tg = t0 + tc * 32;
        #pragma unroll
        for (int p = 0; p < 2; ++p) {
            int tl = st_ + 4 * p;
            float4 v = make_float4(0.f, 0.f, 0.f, 0.f);
            if (tg + tl < TLEN) v = *reinterpret_cast<const float4*>(xrow + tg + tl);
            *reinterpret_cast<float4*>(&xsf[buf][sc_][tl]) = v;
        }
    };

    float m[4], s[4], wx[4], wxx[4];
    #pragma unroll
    for (int i = 0; i < 4; ++i) { m[i] = NINF; s[i] = 0.f; wx[i] = 0.f; wxx[i] = 0.f; }

    stage(0, 0);
    __syncthreads();
    for (int tc = 0; tc < TCHUNK / 32; ++tc) {
        int buf = tc & 1;
        if (tc + 1 < TCHUNK / 32) stage(buf ^ 1, tc + 1);
        f32x4 a2[2];
        a2[0] = f32x4{0.f, 0.f, 0.f, 0.f};
        a2[1] = f32x4{0.f, 0.f, 0.f, 0.f};
        #pragma unroll
        for (int tt = 0; tt < 2; ++tt) {
            int t = t0 + tc * 32 + tt * 16 + r;
            #pragma unroll
            for (int kk = 0; kk < 4; ++kk) {
                bf16x8 Bf = *reinterpret_cast<const bf16x8*>(hb + (size_t)t * ACH + 32 * kk);
                a2[tt] = __builtin_amdgcn_mfma_f32_16x16x32_bf16(W[kk], Bf, a2[tt], 0, 0, 0);
            }
        }
        int tb = t0 + tc * 32 + r;
        bool val0 = (tb < TLEN), val1 = (tb + 16 < TLEN);
        #pragma unroll
        for (int i = 0; i < 4; ++i) {
            int cl = 16 * wv + 4 * g + i;
            float v0 = val0 ? (a2[0][i] + b2v[i]) : NINF;
            float v1 = val1 ? (a2[1][i] + b2v[i]) : NINF;
            float mx = fmaxf(v0, v1);
            if (mx > m[i] + RTHR) {
                float sc = exp2f(m[i] - mx);
                s[i] *= sc; wx[i] *= sc; wxx[i] *= sc; m[i] = mx;
            }
            float e0 = exp2f(v0 - m[i]);
            float e1 = exp2f(v1 - m[i]);
            float x0 = xsf[buf][cl][r];
            float x1 = xsf[buf][cl][r + 16];
            float xe0 = x0 * e0, xe1 = x1 * e1;
            s[i]   += e0 + e1;
            wx[i]  += xe0 + xe1;
            wxx[i] += x0 * xe0 + x1 * xe1;
        }
        __syncthreads();
    }

    #pragma unroll
    for (int i = 0; i < 4; ++i) {
        float mm = m[i], ss = s[i], sx = wx[i], sxx = wxx[i];
        #pragma unroll
        for (int d = 1; d < 16; d <<= 1) {
            float mo = __shfl_xor(mm, d);
            float so = __shfl_xor(ss, d);
            float xo = __shfl_xor(sx, d);
            float qo = __shfl_xor(sxx, d);
            float mn = fmaxf(mm, mo);
            float fa = exp2f(mm - mn), fb = exp2f(mo - mn);
            ss = ss * fa + so * fb;
            sx = sx * fa + xo * fb;
            sxx = sxx * fa + qo * fb;
            mm = mn;
        }
        if (r == 0) {
            int c = c0 + 4 * g + i;
            float4 p; p.x = mm; p.y = ss; p.z = sx; p.w = sxx;
            part[((size_t)(b * TSPLIT + ts)) * CCH + c] = p;
        }
    }
}

// ---------------- E: merge chunk partials + BN2 (nchk runtime)
__global__ __launch_bounds__(256) void kE(const float4* __restrict__ part,
                                          int nchk,
                                          const float* __restrict__ rm2,
                                          const float* __restrict__ rv2,
                                          const float* __restrict__ g2,
                                          const float* __restrict__ be2,
                                          float* __restrict__ out) {
    int idx = blockIdx.x * 256 + threadIdx.x;   // < BATCH*CCH
    int b = idx / CCH, c = idx - b * CCH;
    float m = NINF, s = 0.f, wx = 0.f, wxx = 0.f;
    for (int ts = 0; ts < nchk; ++ts) {
        float4 p = part[((size_t)(b * nchk + ts)) * CCH + c];
        float mn = fmaxf(m, p.x);
        float fa = exp2f(m - mn), fb = exp2f(p.x - mn);
        s = s * fa + p.y * fb;
        wx = wx * fa + p.z * fb;
        wxx = wxx * fa + p.w * fb;
        m = mn;
    }
    float mu = wx / s;
    float ssq = wxx / s;
    float sig = sqrtf(fabsf(ssq - mu * mu) + EPSV);
    out[b * 2 * CCH + c] = (mu - rm2[c]) * g2[c] * rsqrtf(rv2[c] + EPSV) + be2[c];
    int c2 = CCH + c;
    out[b * 2 * CCH + c2] = (sig - rm2[c2]) * g2[c2] * rsqrtf(rv2[c2] + EPSV) + be2[c2];
}

extern "C" void kernel_launch(void* const* d_in, const int* in_sizes, int n_in,
                              void* d_out, int out_size, void* d_ws, size_t ws_size,
                              hipStream_t stream) {
    const float* x   = (const float*)d_in[0];
    const float* w1  = (const float*)d_in[1];
    const float* b1  = (const float*)d_in[2];
    const float* g1  = (const float*)d_in[3];
    const float* be1 = (const float*)d_in[4];
    const float* rm1 = (const float*)d_in[5];
    const float* rv1 = (const float*)d_in[6];
    const float* w2  = (const float*)d_in[7];
    const float* b2  = (const float*)d_in[8];
    const float* g2  = (const float*)d_in[9];
    const float* be2 = (const float*)d_in[10];
    const float* rm2 = (const float*)d_in[11];
    const float* rv2 = (const float*)d_in[12];
    float* out = (float*)d_out;

    const size_t sz_xt    = (size_t)BATCH * NCB * XTB * 2;    // 100.7 MB (blocked layout)
    const size_t sz_h     = (size_t)BATCH * TPAD * ACH * 2;   // 8.4 MB (fallback only)
    const size_t sz_w1x   = (size_t)ACH * CCH * 2;
    const size_t sz_w2e   = (size_t)CCH * ACH * 2;
    const size_t sz_st    = (size_t)TSA * BATCH * CCH * 4;    // stat partials (x2)
    const size_t sz_hbias = (size_t)BATCH * ACH * 4;
    const size_t sz_b2e   = (size_t)CCH * 4;
    const size_t sz_part  = (size_t)BATCH * NCHK * CCH * 16;  // 12.6 MB
    const size_t need_small = sz_h + sz_w1x + sz_w2e + 2 * sz_st
                            + sz_hbias + sz_b2e + sz_part;
    bool use_xt = (ws_size >= need_small + sz_xt);

    char* ws = (char*)d_ws;
    unsigned short* xt = nullptr;
    if (use_xt) { xt = (unsigned short*)ws; ws += sz_xt; }
    unsigned short* hbuf = (unsigned short*)ws; ws += sz_h;
    unsigned short* w1x  = (unsigned short*)ws; ws += sz_w1x;
    unsigned short* w2e  = (unsigned short*)ws; ws += sz_w2e;
    float* st1   = (float*)ws; ws += sz_st;
    float* st2   = (float*)ws; ws += sz_st;
    float* hbias = (float*)ws; ws += sz_hbias;
    float* b2e   = (float*)ws; ws += sz_b2e;
    float4* part = (float4*)ws; ws += sz_part;

    const int NBW = (ACH * CCH) / 256 + CCH / 4;   // 768 + 384
    if (use_xt)
        kA<<<dim3(NCB, BATCH, TSA), 512, 0, stream>>>(x, xt, st1, st2);
    else
        kA2<<<dim3(48, 32), 256, 0, stream>>>(x, st1, st2);
    kBW<<<NBW, 256, 0, stream>>>(w1, w1x, w2, b2, g1, be1, rm1, rv1, w2e, b2e);
    kB2n<<<dim3(ACH, BATCH), 64, 0, stream>>>(w1, b1, st1, st2, hbias);
    if (use_xt) {
        kCD<<<dim3(TPAD / 64, BATCH), 512, 0, stream>>>(xt, w1x, hbias, w2e, b2e, part);
        kE<<<(BATCH * CCH) / 256, 256, 0, stream>>>(part, NCHK, rm2, rv2, g2, be2, out);
    } else {
        kC2<<<dim3(TPAD / 32, BATCH), 256, 0, stream>>>(x, w1x, hbias, hbuf);
        kD1<<<dim3(CCH / 64, BATCH, TSPLIT), 256, 0, stream>>>(x, hbuf, w2e, b2e, part);
        kE<<<(BATCH * CCH) / 256, 256, 0, stream>>>(part, TSPLIT, rm2, rv2, g2, be2, out);
    }
}

// Round 11
// 161.519 us; speedup vs baseline: 1.2072x; 1.2072x over previous
//
#include <hip/hip_runtime.h>
#include <hip/hip_bf16.h>

#define BATCH 32
#define CCH   1536
#define ACH   128
#define TLEN  1000
#define TPAD  1024
#define NCB   (CCH / 64)      // 24 channel blocks in xt layout
#define XTB   (TPAD * 64)     // elements per (b, cblk) panel = 65536
#define TSPLIT 8
#define TCHUNK 128
#define TSA   2               // kA t-split
#define EPSV  1e-5f
#define NINF  -3.0e38f
#define LOG2E 1.4426950408889634f
#define RTHR  11.5f

typedef __attribute__((ext_vector_type(8))) short bf16x8;
typedef __attribute__((ext_vector_type(4))) float f32x4;

__device__ __forceinline__ unsigned short f2bf(float f) {
    union { float f; unsigned u; } v; v.f = f;
    unsigned r = v.u + 0x7fffu + ((v.u >> 16) & 1u);
    return (unsigned short)(r >> 16);
}
__device__ __forceinline__ float bf2f(unsigned short u) {
    union { unsigned u; float f; } v; v.u = ((unsigned)u) << 16;
    return v.f;
}

// ---------------- Kernel A: cast/transpose x -> xt blocked [b][cblk][t][64c] bf16,
// stats accumulated in the LDS READ phase (loads have no same-iteration consumer).
__global__ __launch_bounds__(512) void kA(const float* __restrict__ x,
                                          unsigned short* __restrict__ xt,
                                          float* __restrict__ st1,
                                          float* __restrict__ st2) {
    int b = blockIdx.y, cblk = blockIdx.x, ts = blockIdx.z;
    int cb = cblk * 64;
    int tbase = ts * (TPAD / TSA);             // 0 or 512
    int tid = threadIdx.x;
    int row = tid >> 3, l8 = tid & 7;          // 64 rows (channels), 8 lanes/row
    __shared__ float tile[2][64][65];          // [buf][t][c]
    __shared__ float red1[8][64], red2[8][64]; // per-wave channel partials
    const float* xr = x + ((size_t)(b * CCH + cb + row)) * TLEN + tbase;
    unsigned short* xtp = xt + ((size_t)(b * NCB + cblk)) * XTB + (size_t)tbase * 64;

    float4 rA[2];
    float cs1[8], cs2[8];
    #pragma unroll
    for (int j = 0; j < 8; ++j) { cs1[j] = 0.f; cs2[j] = 0.f; }

    auto loadTile = [&](int it) {
        #pragma unroll
        for (int p = 0; p < 2; ++p) {
            int tf = it * 64 + p * 32 + l8 * 4;
            float4 vv = make_float4(0.f, 0.f, 0.f, 0.f);
            if (tbase + tf < TLEN) vv = *reinterpret_cast<const float4*>(xr + tf);
            rA[p] = vv;                      // no other consumer here: true prefetch
        }
    };
    auto writeTile = [&](int buf) {
        #pragma unroll
        for (int p = 0; p < 2; ++p) {
            int tl = p * 32 + l8 * 4;
            tile[buf][tl + 0][row] = rA[p].x;
            tile[buf][tl + 1][row] = rA[p].y;
            tile[buf][tl + 2][row] = rA[p].z;
            tile[buf][tl + 3][row] = rA[p].w;
        }
    };
    auto readStore = [&](int buf, int it) {
        int tl = tid >> 3;             // 64 t-rows
        int c8 = (tid & 7) * 8;        // 8 channels; contiguous 128B per t-row
        float v[8];
        #pragma unroll
        for (int j = 0; j < 8; ++j) {
            v[j] = tile[buf][tl][c8 + j];
            cs1[j] += v[j];
            cs2[j] += v[j] * v[j];
        }
        unsigned o[4];
        #pragma unroll
        for (int j = 0; j < 4; ++j)
            o[j] = (unsigned)f2bf(v[2 * j]) | ((unsigned)f2bf(v[2 * j + 1]) << 16);
        uint4 u; u.x = o[0]; u.y = o[1]; u.z = o[2]; u.w = o[3];
        *reinterpret_cast<uint4*>(xtp + (size_t)(it * 64 + tl) * 64 + c8) = u;
    };

    const int NIT = (TPAD / TSA) / 64;   // 8
    loadTile(0);
    writeTile(0);
    loadTile(1);
    __syncthreads();
    for (int it = 0; it < NIT; ++it) {
        int buf = it & 1;
        if (it < NIT - 1) writeTile(buf ^ 1);   // consumes loads issued 2 iters ago
        if (it < NIT - 2) loadTile(it + 2);     // pure issue, no wait
        readStore(buf, it);                     // LDS reads + stats + streaming store
        __syncthreads();
    }

    #pragma unroll
    for (int j = 0; j < 8; ++j) {
        #pragma unroll
        for (int d = 8; d < 64; d <<= 1) {
            cs1[j] += __shfl_xor(cs1[j], d);
            cs2[j] += __shfl_xor(cs2[j], d);
        }
    }
    int wv = tid >> 6, lane = tid & 63;
    if (lane < 8) {
        #pragma unroll
        for (int j = 0; j < 8; ++j) {
            red1[wv][lane * 8 + j] = cs1[j];
            red2[wv][lane * 8 + j] = cs2[j];
        }
    }
    __syncthreads();
    if (tid < 64) {
        float s1 = 0.f, s2 = 0.f;
        #pragma unroll
        for (int w = 0; w < 8; ++w) { s1 += red1[w][tid]; s2 += red2[w][tid]; }
        st1[((size_t)ts * BATCH + b) * CCH + cb + tid] = s1;
        st2[((size_t)ts * BATCH + b) * CCH + cb + tid] = s2;
    }
}

// Stats-only fallback (writes st-format partials; second slice zeroed)
__global__ __launch_bounds__(256) void kA2(const float* __restrict__ x,
                                           float* __restrict__ st1,
                                           float* __restrict__ st2) {
    int b = blockIdx.y, cb = blockIdx.x * 32;
    int tid = threadIdx.x;
    int row = tid >> 3, l8 = tid & 7;
    const float* xr = x + ((size_t)(b * CCH + cb + row)) * TLEN;
    float s1 = 0.f, s2 = 0.f;
    for (int tf = l8 * 4; tf < TLEN; tf += 32) {
        float4 vv = *reinterpret_cast<const float4*>(xr + tf);
        s1 += vv.x + vv.y + vv.z + vv.w;
        s2 += vv.x * vv.x + vv.y * vv.y + vv.z * vv.z + vv.w * vv.w;
    }
    #pragma unroll
    for (int d = 1; d < 8; d <<= 1) { s1 += __shfl_xor(s1, d); s2 += __shfl_xor(s2, d); }
    if (l8 == 0) {
        int idx = b * CCH + cb + row;
        st1[idx] = s1;
        st2[idx] = s2;
        st1[(size_t)BATCH * CCH + idx] = 0.f;
        st2[(size_t)BATCH * CCH + idx] = 0.f;
    }
}

// ---------------- BW: fused prep — w1 x-part cast (first 768 blocks) + BN1-folded w2 (next 384)
__global__ __launch_bounds__(256) void kBW(const float* __restrict__ w1,
                                           unsigned short* __restrict__ w1x,
                                           const float* __restrict__ w2,
                                           const float* __restrict__ b2,
                                           const float* __restrict__ g1,
                                           const float* __restrict__ be1,
                                           const float* __restrict__ rm1,
                                           const float* __restrict__ rv1,
                                           unsigned short* __restrict__ w2e,
                                           float* __restrict__ b2e) {
    int bx = blockIdx.x;
    const int NB1 = (ACH * CCH) / 256;   // 768
    if (bx < NB1) {
        int e = bx * 256 + threadIdx.x;
        int a = e / CCH, c = e - a * CCH;
        w1x[e] = f2bf(w1[(size_t)a * (3 * CCH) + c]);
    } else {
        int c = (bx - NB1) * 4 + (threadIdx.x >> 6);   // 4 channels/block, 1 wave each
        int l = threadIdx.x & 63;
        float acc = 0.f;
        #pragma unroll
        for (int p = 0; p < 2; ++p) {
            int a = p * 64 + l;
            float s1 = g1[a] * rsqrtf(rv1[a] + EPSV);
            float w = w2[(size_t)c * ACH + a];
            w2e[(size_t)c * ACH + a] = f2bf(w * s1 * LOG2E);   // logits in log2 units
            acc += w * (be1[a] - s1 * rm1[a]);
        }
        #pragma unroll
        for (int d = 1; d < 64; d <<= 1) acc += __shfl_xor(acc, d);
        if (l == 0) b2e[c] = (b2[c] + acc) * LOG2E;
    }
}

// ---------------- B2n: hbias[b][a] = b1[a] + sum_c w1m*mean + w1s*std
__global__ __launch_bounds__(64) void kB2n(const float* __restrict__ w1,
                                           const float* __restrict__ b1,
                                           const float* __restrict__ st1,
                                           const float* __restrict__ st2,
                                           float* __restrict__ hbias) {
    int a = blockIdx.x, b = blockIdx.y, l = threadIdx.x;
    const float* wr = w1 + (size_t)a * 3 * CCH;
    const float* p1 = st1 + (size_t)b * CCH;
    const float* p2 = st2 + (size_t)b * CCH;
    const size_t half = (size_t)BATCH * CCH;
    float acc = 0.f;
    const float invT = 1.f / (float)TLEN;
    const float invT1 = 1.f / (float)(TLEN - 1);
    for (int k = l; k < CCH; k += 64) {
        float s1 = p1[k] + p1[half + k];
        float s2 = p2[k] + p2[half + k];
        float mean = s1 * invT;
        float var = (s2 - s1 * s1 * invT) * invT1;
        float stdv = sqrtf(var + EPSV);
        acc += wr[CCH + k] * mean + wr[2 * CCH + k] * stdv;
    }
    #pragma unroll
    for (int d = 1; d < 64; d <<= 1) acc += __shfl_xor(acc, d);
    if (l == 0) hbias[b * ACH + a] = acc + b1[a];
}

// ---------------- C3: GEMM1 h[b][t][a] = relu(w1x @ xt^T + hbias), LDS-staged MFMA
__global__ __launch_bounds__(512) void kC3(const unsigned short* __restrict__ xt,
                                           const unsigned short* __restrict__ w1x,
                                           const float* __restrict__ hbias,
                                           unsigned short* __restrict__ h) {
    int b = blockIdx.y;
    int t0 = blockIdx.x * 64;
    int tid = threadIdx.x;
    int wv = tid >> 6, l = tid & 63, g = l >> 4, r = l & 15;
    int a0 = (wv & 3) * 32;
    int tw = (wv >> 2) * 32;

    __shared__ uint4 As[2][1024];   // [128a][64c] bf16, swizzled 16B chunks (8/row)
    __shared__ uint4 Bs[2][512];    // [64t][64c]  bf16, swizzled

    const unsigned short* bG = xt + (size_t)b * NCB * XTB;   // panel base for batch b

    int qa0 = tid, qa1 = tid + 512, qb = tid;
    int wa0 = qa0 ^ ((qa0 >> 3) & 7), wa1 = qa1 ^ ((qa1 >> 3) & 7), wb = qb ^ ((qb >> 3) & 7);
    int arow0 = qa0 >> 3, arow1 = qa1 >> 3, acol = (qa0 & 7) * 8;
    int brow = qb >> 3, bcol = (qb & 7) * 8;

    As[0][wa0] = *reinterpret_cast<const uint4*>(w1x + (size_t)arow0 * CCH + acol);
    As[0][wa1] = *reinterpret_cast<const uint4*>(w1x + (size_t)arow1 * CCH + acol);
    Bs[0][wb]  = *reinterpret_cast<const uint4*>(bG + (size_t)(t0 + brow) * 64 + bcol);
    __syncthreads();

    f32x4 acc[2][2];
    #pragma unroll
    for (int i = 0; i < 2; ++i)
        #pragma unroll
        for (int j = 0; j < 2; ++j) acc[i][j] = f32x4{0.f, 0.f, 0.f, 0.f};

    for (int ks = 0; ks < CCH / 64; ++ks) {
        int buf = ks & 1;
        uint4 na0, na1, nb;
        if (ks < CCH / 64 - 1) {
            int cofs = (ks + 1) * 64;
            na0 = *reinterpret_cast<const uint4*>(w1x + (size_t)arow0 * CCH + cofs + acol);
            na1 = *reinterpret_cast<const uint4*>(w1x + (size_t)arow1 * CCH + cofs + acol);
            nb  = *reinterpret_cast<const uint4*>(bG + (size_t)(ks + 1) * XTB + (size_t)(t0 + brow) * 64 + bcol);
        }
        bf16x8 Af[2][2], Bf[2][2];
        #pragma unroll
        for (int at = 0; at < 2; ++at) {
            int row = a0 + 16 * at + r;
            #pragma unroll
            for (int kk = 0; kk < 2; ++kk) {
                int ch = (row * 8 + kk * 4 + g) ^ (row & 7);
                Af[at][kk] = *reinterpret_cast<const bf16x8*>(&As[buf][ch]);
            }
        }
        #pragma unroll
        for (int tt = 0; tt < 2; ++tt) {
            int row = tw + 16 * tt + r;
            #pragma unroll
            for (int kk = 0; kk < 2; ++kk) {
                int ch = (row * 8 + kk * 4 + g) ^ (row & 7);
                Bf[tt][kk] = *reinterpret_cast<const bf16x8*>(&Bs[buf][ch]);
            }
        }
        #pragma unroll
        for (int kk = 0; kk < 2; ++kk)
            #pragma unroll
            for (int at = 0; at < 2; ++at)
                #pragma unroll
                for (int tt = 0; tt < 2; ++tt)
                    acc[at][tt] = __builtin_amdgcn_mfma_f32_16x16x32_bf16(Af[at][kk], Bf[tt][kk], acc[at][tt], 0, 0, 0);
        if (ks < CCH / 64 - 1) {
            As[buf ^ 1][wa0] = na0;
            As[buf ^ 1][wa1] = na1;
            Bs[buf ^ 1][wb]  = nb;
        }
        __syncthreads();
    }

    #pragma unroll
    for (int at = 0; at < 2; ++at) {
        f32x4 hb = *reinterpret_cast<const f32x4*>(hbias + b * ACH + a0 + 16 * at + 4 * g);
        #pragma unroll
        for (int tt = 0; tt < 2; ++tt) {
            int t = t0 + tw + 16 * tt + r;
            float v0 = acc[at][tt][0] + hb[0]; v0 = v0 > 0.f ? v0 : 0.f;
            float v1 = acc[at][tt][1] + hb[1]; v1 = v1 > 0.f ? v1 : 0.f;
            float v2 = acc[at][tt][2] + hb[2]; v2 = v2 > 0.f ? v2 : 0.f;
            float v3 = acc[at][tt][3] + hb[3]; v3 = v3 > 0.f ? v3 : 0.f;
            uint2 u;
            u.x = (unsigned)f2bf(v0) | ((unsigned)f2bf(v1) << 16);
            u.y = (unsigned)f2bf(v2) | ((unsigned)f2bf(v3) << 16);
            *reinterpret_cast<uint2*>(h + ((size_t)(b * TPAD + t)) * ACH + a0 + 16 * at + 4 * g) = u;
        }
    }
}

// Fallback GEMM1: gather x fp32 directly (slow but correct), used if no room for xt
__global__ __launch_bounds__(256) void kC2(const float* __restrict__ x,
                                           const unsigned short* __restrict__ w1x,
                                           const float* __restrict__ hbias,
                                           unsigned short* __restrict__ h) {
    int b = blockIdx.y;
    int t0 = blockIdx.x * 32;
    int tid = threadIdx.x;
    int wv = tid >> 6, l = tid & 63, g = l >> 4, r = l & 15;
    const unsigned short* aptr = w1x + (size_t)(32 * wv + r) * CCH + 8 * g;
    f32x4 acc[2][2];
    #pragma unroll
    for (int i = 0; i < 2; ++i)
        #pragma unroll
        for (int j = 0; j < 2; ++j) acc[i][j] = f32x4{0.f, 0.f, 0.f, 0.f};
    for (int kk = 0; kk < CCH / 32; ++kk) {
        bf16x8 Af[2], Bf[2];
        #pragma unroll
        for (int at = 0; at < 2; ++at)
            Af[at] = *reinterpret_cast<const bf16x8*>(aptr + (size_t)(16 * at) * CCH + 32 * kk);
        #pragma unroll
        for (int tt = 0; tt < 2; ++tt) {
            int t = t0 + 16 * tt + r;
            unsigned short tmp[8];
            #pragma unroll
            for (int j = 0; j < 8; ++j) {
                float xv = 0.f;
                if (t < TLEN) xv = x[((size_t)(b * CCH + 32 * kk + 8 * g + j)) * TLEN + t];
                tmp[j] = f2bf(xv);
            }
            Bf[tt] = *reinterpret_cast<const bf16x8*>(tmp);
        }
        #pragma unroll
        for (int at = 0; at < 2; ++at)
            #pragma unroll
            for (int tt = 0; tt < 2; ++tt)
                acc[at][tt] = __builtin_amdgcn_mfma_f32_16x16x32_bf16(Af[at], Bf[tt], acc[at][tt], 0, 0, 0);
    }
    #pragma unroll
    for (int at = 0; at < 2; ++at) {
        f32x4 hb = *reinterpret_cast<const f32x4*>(hbias + b * ACH + 32 * wv + 16 * at + 4 * g);
        #pragma unroll
        for (int tt = 0; tt < 2; ++tt) {
            int t = t0 + 16 * tt + r;
            float v0 = acc[at][tt][0] + hb[0]; v0 = v0 > 0.f ? v0 : 0.f;
            float v1 = acc[at][tt][1] + hb[1]; v1 = v1 > 0.f ? v1 : 0.f;
            float v2 = acc[at][tt][2] + hb[2]; v2 = v2 > 0.f ? v2 : 0.f;
            float v3 = acc[at][tt][3] + hb[3]; v3 = v3 > 0.f ? v3 : 0.f;
            uint2 u;
            u.x = (unsigned)f2bf(v0) | ((unsigned)f2bf(v1) << 16);
            u.y = (unsigned)f2bf(v2) | ((unsigned)f2bf(v3) << 16);
            *reinterpret_cast<uint2*>(h + ((size_t)(b * TPAD + t)) * ACH + 32 * wv + 16 * at + 4 * g) = u;
        }
    }
}

// ---------------- D4: GEMM2 + online softmax partials; BOTH h and x staged through
// swizzled LDS with coalesced chunk loads (x chunk = 2 contiguous 4KB panels).
// block: 128 channels x 128 t-chunk; 4 waves; grid (CCH/128, B, TSPLIT=8)
__global__ __launch_bounds__(256) void kD4(const unsigned short* __restrict__ xt,
                                           const unsigned short* __restrict__ h,
                                           const unsigned short* __restrict__ w2e,
                                           const float* __restrict__ b2e,
                                           float4* __restrict__ part) {
    int b = blockIdx.y, ts = blockIdx.z;
    int cblk = blockIdx.x * 128;
    int tid = threadIdx.x;
    int wv = tid >> 6, l = tid & 63, g = l >> 4, r = l & 15;
    int c0 = cblk + 32 * wv;
    int t0 = ts * TCHUNK;

    __shared__ uint4 hs[2][512];    // [32t][128a] bf16, swizzled 16B chunks (16/row)
    __shared__ uint2 xs[2][1024];   // [32t][128c] bf16, swizzled 8B granules

    bf16x8 W[2][4];
    f32x4 b2v[2];
    #pragma unroll
    for (int af = 0; af < 2; ++af) {
        #pragma unroll
        for (int kk = 0; kk < 4; ++kk)
            W[af][kk] = *reinterpret_cast<const bf16x8*>(w2e + (size_t)(c0 + 16 * af + r) * ACH + 32 * kk + 8 * g);
        b2v[af] = *reinterpret_cast<const f32x4*>(b2e + c0 + 16 * af + 4 * g);
    }

    const unsigned short* hbase = h + (size_t)(b * TPAD + t0) * ACH;
    const unsigned short* xpan = xt + ((size_t)b * NCB + (cblk >> 6)) * XTB;  // 2 panels

    // h staging indices
    int q0 = tid, q1 = tid + 256;
    int w0 = q0 ^ ((q0 >> 4) & 7), w1 = q1 ^ ((q1 >> 4) & 7);
    // x staging indices: thread covers (t=tid>>3, c8=tid&7) in panel 0 and panel 1
    int xtl = tid >> 3, xw7 = tid & 7;
    int xc0 = (xtl * 16 + xw7) ^ (xtl & 7);        // panel 0 chunk
    int xc1 = (xtl * 16 + 8 + xw7) ^ (xtl & 7);    // panel 1 chunk
    // x read granule indices (uint2): element (t,c): granule (t*32 + (c>>2)) ^ ((t&7)<<1)
    int xg[2];
    #pragma unroll
    for (int af = 0; af < 2; ++af) {
        int gx = 8 * wv + 4 * af + g;              // c_local>>2
        xg[af] = (r * 32 + gx) ^ ((r & 7) << 1);   // t_local = r; +512 for r+16
    }

    auto ldH = [&](int tc, uint4& a, uint4& bq) {
        const unsigned short* src = hbase + (size_t)tc * 32 * ACH;
        a  = *reinterpret_cast<const uint4*>(src + q0 * 8);
        bq = *reinterpret_cast<const uint4*>(src + q1 * 8);
    };
    auto ldX = [&](int tc, uint4& a, uint4& bq) {
        size_t off = (size_t)(t0 + tc * 32 + xtl) * 64 + xw7 * 8;
        a  = *reinterpret_cast<const uint4*>(xpan + off);
        bq = *reinterpret_cast<const uint4*>(xpan + XTB + off);
    };

    {
        uint4 h0, h1, x0, x1;
        ldH(0, h0, h1); ldX(0, x0, x1);
        hs[0][w0] = h0; hs[0][w1] = h1;
        *reinterpret_cast<uint4*>(&xs[0][2 * xc0]) = x0;
        *reinterpret_cast<uint4*>(&xs[0][2 * xc1]) = x1;
    }
    __syncthreads();

    float m[2][4], s[2][4], wx[2][4], wxx[2][4];
    #pragma unroll
    for (int af = 0; af < 2; ++af)
        #pragma unroll
        for (int i = 0; i < 4; ++i) { m[af][i] = NINF; s[af][i] = 0.f; wx[af][i] = 0.f; wxx[af][i] = 0.f; }

    for (int tc = 0; tc < TCHUNK / 32; ++tc) {
        int buf = tc & 1;
        uint4 nh0, nh1, nx0, nx1;
        if (tc < TCHUNK / 32 - 1) {
            ldH(tc + 1, nh0, nh1);
            ldX(tc + 1, nx0, nx1);
        }

        f32x4 a2[2][2];
        a2[0][0] = f32x4{0.f, 0.f, 0.f, 0.f}; a2[0][1] = f32x4{0.f, 0.f, 0.f, 0.f};
        a2[1][0] = f32x4{0.f, 0.f, 0.f, 0.f}; a2[1][1] = f32x4{0.f, 0.f, 0.f, 0.f};
        #pragma unroll
        for (int tt = 0; tt < 2; ++tt) {
            int tl = tt * 16 + r;
            #pragma unroll
            for (int kk = 0; kk < 4; ++kk) {
                int ch = (tl * 16 + kk * 4 + g) ^ (tl & 7);
                bf16x8 Bf = *reinterpret_cast<const bf16x8*>(&hs[buf][ch]);
                a2[0][tt] = __builtin_amdgcn_mfma_f32_16x16x32_bf16(W[0][kk], Bf, a2[0][tt], 0, 0, 0);
                a2[1][tt] = __builtin_amdgcn_mfma_f32_16x16x32_bf16(W[1][kk], Bf, a2[1][tt], 0, 0, 0);
            }
        }

        int tb0 = t0 + tc * 32 + r, tb1 = tb0 + 16;
        bool val0 = (tb0 < TLEN), val1 = (tb1 < TLEN);
        #pragma unroll
        for (int af = 0; af < 2; ++af) {
            uint2 xu0 = xs[buf][xg[af]];
            uint2 xu1 = xs[buf][xg[af] + 512];
            float xv0[4], xv1[4];
            xv0[0] = bf2f((unsigned short)(xu0.x & 0xffff));
            xv0[1] = bf2f((unsigned short)(xu0.x >> 16));
            xv0[2] = bf2f((unsigned short)(xu0.y & 0xffff));
            xv0[3] = bf2f((unsigned short)(xu0.y >> 16));
            xv1[0] = bf2f((unsigned short)(xu1.x & 0xffff));
            xv1[1] = bf2f((unsigned short)(xu1.x >> 16));
            xv1[2] = bf2f((unsigned short)(xu1.y & 0xffff));
            xv1[3] = bf2f((unsigned short)(xu1.y >> 16));
            #pragma unroll
            for (int i = 0; i < 4; ++i) {
                float v0 = val0 ? (a2[af][0][i] + b2v[af][i]) : NINF;
                float v1 = val1 ? (a2[af][1][i] + b2v[af][i]) : NINF;
                float mx = fmaxf(v0, v1);
                if (__any(mx > m[af][i] + RTHR)) {   // wave-uniform deferred rescale (T13)
                    float mn = fmaxf(m[af][i], mx);
                    float sc = exp2f(m[af][i] - mn);
                    s[af][i] *= sc; wx[af][i] *= sc; wxx[af][i] *= sc; m[af][i] = mn;
                }
                float e0 = exp2f(v0 - m[af][i]);
                float e1 = exp2f(v1 - m[af][i]);
                float xe0 = xv0[i] * e0, xe1 = xv1[i] * e1;
                s[af][i]   += e0 + e1;
                wx[af][i]  += xe0 + xe1;
                wxx[af][i] += xv0[i] * xe0 + xv1[i] * xe1;
            }
        }

        if (tc < TCHUNK / 32 - 1) {
            hs[buf ^ 1][w0] = nh0;
            hs[buf ^ 1][w1] = nh1;
            *reinterpret_cast<uint4*>(&xs[buf ^ 1][2 * xc0]) = nx0;
            *reinterpret_cast<uint4*>(&xs[buf ^ 1][2 * xc1]) = nx1;
        }
        __syncthreads();
    }

    // merge across the 16 lanes (r) that share each channel
    #pragma unroll
    for (int af = 0; af < 2; ++af)
        #pragma unroll
        for (int i = 0; i < 4; ++i) {
            float mm = m[af][i], ss = s[af][i], sx = wx[af][i], sxx = wxx[af][i];
            #pragma unroll
            for (int d = 1; d < 16; d <<= 1) {
                float mo = __shfl_xor(mm, d);
                float so = __shfl_xor(ss, d);
                float xo = __shfl_xor(sx, d);
                float qo = __shfl_xor(sxx, d);
                float mn = fmaxf(mm, mo);
                float fa = exp2f(mm - mn), fb = exp2f(mo - mn);
                ss = ss * fa + so * fb;
                sx = sx * fa + xo * fb;
                sxx = sxx * fa + qo * fb;
                mm = mn;
            }
            if (r == 0) {
                int c = c0 + 16 * af + 4 * g + i;
                float4 p; p.x = mm; p.y = ss; p.z = sx; p.w = sxx;
                part[((size_t)(b * TSPLIT + ts)) * CCH + c] = p;
            }
        }
}

// Fallback D (reads fp32 x via LDS staging) — used only when xt doesn't fit
__global__ __launch_bounds__(256) void kD1(const float* __restrict__ x,
                                           const unsigned short* __restrict__ h,
                                           const unsigned short* __restrict__ w2e,
                                           const float* __restrict__ b2e,
                                           float4* __restrict__ part) {
    int b = blockIdx.y, ts = blockIdx.z;
    int cblk = blockIdx.x * 64;
    int tid = threadIdx.x;
    int wv = tid >> 6, l = tid & 63, g = l >> 4, r = l & 15;
    int c0 = cblk + 16 * wv;
    int t0 = ts * TCHUNK;
    __shared__ float xsf[2][64][36];

    bf16x8 W[4];
    #pragma unroll
    for (int kk = 0; kk < 4; ++kk)
        W[kk] = *reinterpret_cast<const bf16x8*>(w2e + (size_t)(c0 + r) * ACH + 32 * kk + 8 * g);
    f32x4 b2v = *reinterpret_cast<const f32x4*>(b2e + c0 + 4 * g);

    int sc_ = tid >> 2;
    int st_ = (tid & 3) * 8;
    const float* xrow = x + ((size_t)(b * CCH + cblk + sc_)) * TLEN;
    const unsigned short* hb = h + (size_t)(b * TPAD) * ACH + 8 * g;

    auto stage = [&](int buf, int tc) {
        int tg = t0 + tc * 32;
        #pragma unroll
        for (int p = 0; p < 2; ++p) {
            int tl = st_ + 4 * p;
            float4 v = make_float4(0.f, 0.f, 0.f, 0.f);
            if (tg + tl < TLEN) v = *reinterpret_cast<const float4*>(xrow + tg + tl);
            *reinterpret_cast<float4*>(&xsf[buf][sc_][tl]) = v;
        }
    };

    float m[4], s[4], wx[4], wxx[4];
    #pragma unroll
    for (int i = 0; i < 4; ++i) { m[i] = NINF; s[i] = 0.f; wx[i] = 0.f; wxx[i] = 0.f; }

    stage(0, 0);
    __syncthreads();
    for (int tc = 0; tc < TCHUNK / 32; ++tc) {
        int buf = tc & 1;
        if (tc + 1 < TCHUNK / 32) stage(buf ^ 1, tc + 1);
        f32x4 a2[2];
        a2[0] = f32x4{0.f, 0.f, 0.f, 0.f};
        a2[1] = f32x4{0.f, 0.f, 0.f, 0.f};
        #pragma unroll
        for (int tt = 0; tt < 2; ++tt) {
            int t = t0 + tc * 32 + tt * 16 + r;
            #pragma unroll
            for (int kk = 0; kk < 4; ++kk) {
                bf16x8 Bf = *reinterpret_cast<const bf16x8*>(hb + (size_t)t * ACH + 32 * kk);
                a2[tt] = __builtin_amdgcn_mfma_f32_16x16x32_bf16(W[kk], Bf, a2[tt], 0, 0, 0);
            }
        }
        int tb = t0 + tc * 32 + r;
        bool val0 = (tb < TLEN), val1 = (tb + 16 < TLEN);
        #pragma unroll
        for (int i = 0; i < 4; ++i) {
            int cl = 16 * wv + 4 * g + i;
            float v0 = val0 ? (a2[0][i] + b2v[i]) : NINF;
            float v1 = val1 ? (a2[1][i] + b2v[i]) : NINF;
            float mx = fmaxf(v0, v1);
            if (mx > m[i] + RTHR) {
                float sc = exp2f(m[i] - mx);
                s[i] *= sc; wx[i] *= sc; wxx[i] *= sc; m[i] = mx;
            }
            float e0 = exp2f(v0 - m[i]);
            float e1 = exp2f(v1 - m[i]);
            float x0 = xsf[buf][cl][r];
            float x1 = xsf[buf][cl][r + 16];
            float xe0 = x0 * e0, xe1 = x1 * e1;
            s[i]   += e0 + e1;
            wx[i]  += xe0 + xe1;
            wxx[i] += x0 * xe0 + x1 * xe1;
        }
        __syncthreads();
    }

    #pragma unroll
    for (int i = 0; i < 4; ++i) {
        float mm = m[i], ss = s[i], sx = wx[i], sxx = wxx[i];
        #pragma unroll
        for (int d = 1; d < 16; d <<= 1) {
            float mo = __shfl_xor(mm, d);
            float so = __shfl_xor(ss, d);
            float xo = __shfl_xor(sx, d);
            float qo = __shfl_xor(sxx, d);
            float mn = fmaxf(mm, mo);
            float fa = exp2f(mm - mn), fb = exp2f(mo - mn);
            ss = ss * fa + so * fb;
            sx = sx * fa + xo * fb;
            sxx = sxx * fa + qo * fb;
            mm = mn;
        }
        if (r == 0) {
            int c = c0 + 4 * g + i;
            float4 p; p.x = mm; p.y = ss; p.z = sx; p.w = sxx;
            part[((size_t)(b * TSPLIT + ts)) * CCH + c] = p;
        }
    }
}

// ---------------- E: merge T-chunk partials + BN2
__global__ __launch_bounds__(256) void kE(const float4* __restrict__ part,
                                          const float* __restrict__ rm2,
                                          const float* __restrict__ rv2,
                                          const float* __restrict__ g2,
                                          const float* __restrict__ be2,
                                          float* __restrict__ out) {
    int idx = blockIdx.x * 256 + threadIdx.x;   // < BATCH*CCH
    int b = idx / CCH, c = idx - b * CCH;
    float m = NINF, s = 0.f, wx = 0.f, wxx = 0.f;
    #pragma unroll
    for (int ts = 0; ts < TSPLIT; ++ts) {
        float4 p = part[((size_t)(b * TSPLIT + ts)) * CCH + c];
        float mn = fmaxf(m, p.x);
        float fa = exp2f(m - mn), fb = exp2f(p.x - mn);
        s = s * fa + p.y * fb;
        wx = wx * fa + p.z * fb;
        wxx = wxx * fa + p.w * fb;
        m = mn;
    }
    float mu = wx / s;
    float ssq = wxx / s;
    float sig = sqrtf(fabsf(ssq - mu * mu) + EPSV);
    out[b * 2 * CCH + c] = (mu - rm2[c]) * g2[c] * rsqrtf(rv2[c] + EPSV) + be2[c];
    int c2 = CCH + c;
    out[b * 2 * CCH + c2] = (sig - rm2[c2]) * g2[c2] * rsqrtf(rv2[c2] + EPSV) + be2[c2];
}

extern "C" void kernel_launch(void* const* d_in, const int* in_sizes, int n_in,
                              void* d_out, int out_size, void* d_ws, size_t ws_size,
                              hipStream_t stream) {
    const float* x   = (const float*)d_in[0];
    const float* w1  = (const float*)d_in[1];
    const float* b1  = (const float*)d_in[2];
    const float* g1  = (const float*)d_in[3];
    const float* be1 = (const float*)d_in[4];
    const float* rm1 = (const float*)d_in[5];
    const float* rv1 = (const float*)d_in[6];
    const float* w2  = (const float*)d_in[7];
    const float* b2  = (const float*)d_in[8];
    const float* g2  = (const float*)d_in[9];
    const float* be2 = (const float*)d_in[10];
    const float* rm2 = (const float*)d_in[11];
    const float* rv2 = (const float*)d_in[12];
    float* out = (float*)d_out;

    const size_t sz_xt    = (size_t)BATCH * NCB * XTB * 2;    // 100.7 MB (blocked layout)
    const size_t sz_h     = (size_t)BATCH * TPAD * ACH * 2;   // 8.4 MB
    const size_t sz_w1x   = (size_t)ACH * CCH * 2;
    const size_t sz_w2e   = (size_t)CCH * ACH * 2;
    const size_t sz_st    = (size_t)TSA * BATCH * CCH * 4;    // stat partials (x2)
    const size_t sz_hbias = (size_t)BATCH * ACH * 4;
    const size_t sz_b2e   = (size_t)CCH * 4;
    const size_t sz_part  = (size_t)BATCH * TSPLIT * CCH * 16; // 6.3 MB
    const size_t need_small = sz_h + sz_w1x + sz_w2e + 2 * sz_st
                            + sz_hbias + sz_b2e + sz_part;
    bool use_xt = (ws_size >= need_small + sz_xt);

    char* ws = (char*)d_ws;
    unsigned short* xt = nullptr;
    if (use_xt) { xt = (unsigned short*)ws; ws += sz_xt; }
    unsigned short* hbuf = (unsigned short*)ws; ws += sz_h;
    unsigned short* w1x  = (unsigned short*)ws; ws += sz_w1x;
    unsigned short* w2e  = (unsigned short*)ws; ws += sz_w2e;
    float* st1   = (float*)ws; ws += sz_st;
    float* st2   = (float*)ws; ws += sz_st;
    float* hbias = (float*)ws; ws += sz_hbias;
    float* b2e   = (float*)ws; ws += sz_b2e;
    float4* part = (float4*)ws; ws += sz_part;

    const int NBW = (ACH * CCH) / 256 + CCH / 4;   // 768 + 384
    if (use_xt)
        kA<<<dim3(NCB, BATCH, TSA), 512, 0, stream>>>(x, xt, st1, st2);
    else
        kA2<<<dim3(48, 32), 256, 0, stream>>>(x, st1, st2);
    kBW<<<NBW, 256, 0, stream>>>(w1, w1x, w2, b2, g1, be1, rm1, rv1, w2e, b2e);
    kB2n<<<dim3(ACH, BATCH), 64, 0, stream>>>(w1, b1, st1, st2, hbias);
    if (use_xt) {
        kC3<<<dim3(TPAD / 64, BATCH), 512, 0, stream>>>(xt, w1x, hbias, hbuf);
        kD4<<<dim3(CCH / 128, BATCH, TSPLIT), 256, 0, stream>>>(xt, hbuf, w2e, b2e, part);
    } else {
        kC2<<<dim3(TPAD / 32, BATCH), 256, 0, stream>>>(x, w1x, hbias, hbuf);
        kD1<<<dim3(CCH / 64, BATCH, TSPLIT), 256, 0, stream>>>(x, hbuf, w2e, b2e, part);
    }
    kE<<<(BATCH * CCH) / 256, 256, 0, stream>>>(part, rm2, rv2, g2, be2, out);
}

// Round 12
// 143.266 us; speedup vs baseline: 1.3610x; 1.1274x over previous
//
#include <hip/hip_runtime.h>
#include <hip/hip_bf16.h>

#define BATCH 32
#define CCH   1536
#define ACH   128
#define TLEN  1000
#define TPAD  1024
#define NCB   (CCH / 64)      // 24 channel blocks in xt layout
#define XTB   (TPAD * 64)     // elements per (b, cblk) panel = 65536
#define TSPLIT 4
#define TCHUNK 256
#define TSA   2               // kA t-split
#define EPSV  1e-5f
#define NINF  -3.0e38f
#define LOG2E 1.4426950408889634f
#define RTHR  11.5f

typedef __attribute__((ext_vector_type(8))) short bf16x8;
typedef __attribute__((ext_vector_type(4))) float f32x4;

__device__ __forceinline__ unsigned short f2bf(float f) {
    union { float f; unsigned u; } v; v.f = f;
    unsigned r = v.u + 0x7fffu + ((v.u >> 16) & 1u);
    return (unsigned short)(r >> 16);
}
__device__ __forceinline__ float bf2f(unsigned short u) {
    union { unsigned u; float f; } v; v.u = ((unsigned)u) << 16;
    return v.f;
}

// ---------------- Kernel A: cast/transpose x -> xt blocked [b][cblk][t][64c] bf16,
// stats accumulated in the LDS READ phase (loads have no same-iteration consumer).
__global__ __launch_bounds__(512) void kA(const float* __restrict__ x,
                                          unsigned short* __restrict__ xt,
                                          float* __restrict__ st1,
                                          float* __restrict__ st2) {
    int b = blockIdx.y, cblk = blockIdx.x, ts = blockIdx.z;
    int cb = cblk * 64;
    int tbase = ts * (TPAD / TSA);             // 0 or 512
    int tid = threadIdx.x;
    int row = tid >> 3, l8 = tid & 7;          // 64 rows (channels), 8 lanes/row
    __shared__ float tile[2][64][65];          // [buf][t][c]
    __shared__ float red1[8][64], red2[8][64]; // per-wave channel partials
    const float* xr = x + ((size_t)(b * CCH + cb + row)) * TLEN + tbase;
    unsigned short* xtp = xt + ((size_t)(b * NCB + cblk)) * XTB + (size_t)tbase * 64;

    float4 rA[2];
    float cs1[8], cs2[8];
    #pragma unroll
    for (int j = 0; j < 8; ++j) { cs1[j] = 0.f; cs2[j] = 0.f; }

    auto loadTile = [&](int it) {
        #pragma unroll
        for (int p = 0; p < 2; ++p) {
            int tf = it * 64 + p * 32 + l8 * 4;
            float4 vv = make_float4(0.f, 0.f, 0.f, 0.f);
            if (tbase + tf < TLEN) vv = *reinterpret_cast<const float4*>(xr + tf);
            rA[p] = vv;                      // no other consumer here: true prefetch
        }
    };
    auto writeTile = [&](int buf) {
        #pragma unroll
        for (int p = 0; p < 2; ++p) {
            int tl = p * 32 + l8 * 4;
            tile[buf][tl + 0][row] = rA[p].x;
            tile[buf][tl + 1][row] = rA[p].y;
            tile[buf][tl + 2][row] = rA[p].z;
            tile[buf][tl + 3][row] = rA[p].w;
        }
    };
    auto readStore = [&](int buf, int it) {
        int tl = tid >> 3;             // 64 t-rows
        int c8 = (tid & 7) * 8;        // 8 channels; contiguous 128B per t-row
        float v[8];
        #pragma unroll
        for (int j = 0; j < 8; ++j) {
            v[j] = tile[buf][tl][c8 + j];
            cs1[j] += v[j];
            cs2[j] += v[j] * v[j];
        }
        unsigned o[4];
        #pragma unroll
        for (int j = 0; j < 4; ++j)
            o[j] = (unsigned)f2bf(v[2 * j]) | ((unsigned)f2bf(v[2 * j + 1]) << 16);
        uint4 u; u.x = o[0]; u.y = o[1]; u.z = o[2]; u.w = o[3];
        *reinterpret_cast<uint4*>(xtp + (size_t)(it * 64 + tl) * 64 + c8) = u;
    };

    const int NIT = (TPAD / TSA) / 64;   // 8
    loadTile(0);
    writeTile(0);
    loadTile(1);
    __syncthreads();
    for (int it = 0; it < NIT; ++it) {
        int buf = it & 1;
        if (it < NIT - 1) writeTile(buf ^ 1);   // consumes loads issued 2 iters ago
        if (it < NIT - 2) loadTile(it + 2);     // pure issue, no wait
        readStore(buf, it);                     // LDS reads + stats + streaming store
        __syncthreads();
    }

    #pragma unroll
    for (int j = 0; j < 8; ++j) {
        #pragma unroll
        for (int d = 8; d < 64; d <<= 1) {
            cs1[j] += __shfl_xor(cs1[j], d);
            cs2[j] += __shfl_xor(cs2[j], d);
        }
    }
    int wv = tid >> 6, lane = tid & 63;
    if (lane < 8) {
        #pragma unroll
        for (int j = 0; j < 8; ++j) {
            red1[wv][lane * 8 + j] = cs1[j];
            red2[wv][lane * 8 + j] = cs2[j];
        }
    }
    __syncthreads();
    if (tid < 64) {
        float s1 = 0.f, s2 = 0.f;
        #pragma unroll
        for (int w = 0; w < 8; ++w) { s1 += red1[w][tid]; s2 += red2[w][tid]; }
        st1[((size_t)ts * BATCH + b) * CCH + cb + tid] = s1;
        st2[((size_t)ts * BATCH + b) * CCH + cb + tid] = s2;
    }
}

// Stats-only fallback (writes st-format partials; second slice zeroed)
__global__ __launch_bounds__(256) void kA2(const float* __restrict__ x,
                                           float* __restrict__ st1,
                                           float* __restrict__ st2) {
    int b = blockIdx.y, cb = blockIdx.x * 32;
    int tid = threadIdx.x;
    int row = tid >> 3, l8 = tid & 7;
    const float* xr = x + ((size_t)(b * CCH + cb + row)) * TLEN;
    float s1 = 0.f, s2 = 0.f;
    for (int tf = l8 * 4; tf < TLEN; tf += 32) {
        float4 vv = *reinterpret_cast<const float4*>(xr + tf);
        s1 += vv.x + vv.y + vv.z + vv.w;
        s2 += vv.x * vv.x + vv.y * vv.y + vv.z * vv.z + vv.w * vv.w;
    }
    #pragma unroll
    for (int d = 1; d < 8; d <<= 1) { s1 += __shfl_xor(s1, d); s2 += __shfl_xor(s2, d); }
    if (l8 == 0) {
        int idx = b * CCH + cb + row;
        st1[idx] = s1;
        st2[idx] = s2;
        st1[(size_t)BATCH * CCH + idx] = 0.f;
        st2[(size_t)BATCH * CCH + idx] = 0.f;
    }
}

// ---------------- BW: fused prep — w1 x-part cast (first 768 blocks) + BN1-folded w2 (next 384)
__global__ __launch_bounds__(256) void kBW(const float* __restrict__ w1,
                                           unsigned short* __restrict__ w1x,
                                           const float* __restrict__ w2,
                                           const float* __restrict__ b2,
                                           const float* __restrict__ g1,
                                           const float* __restrict__ be1,
                                           const float* __restrict__ rm1,
                                           const float* __restrict__ rv1,
                                           unsigned short* __restrict__ w2e,
                                           float* __restrict__ b2e) {
    int bx = blockIdx.x;
    const int NB1 = (ACH * CCH) / 256;   // 768
    if (bx < NB1) {
        int e = bx * 256 + threadIdx.x;
        int a = e / CCH, c = e - a * CCH;
        w1x[e] = f2bf(w1[(size_t)a * (3 * CCH) + c]);
    } else {
        int c = (bx - NB1) * 4 + (threadIdx.x >> 6);   // 4 channels/block, 1 wave each
        int l = threadIdx.x & 63;
        float acc = 0.f;
        #pragma unroll
        for (int p = 0; p < 2; ++p) {
            int a = p * 64 + l;
            float s1 = g1[a] * rsqrtf(rv1[a] + EPSV);
            float w = w2[(size_t)c * ACH + a];
            w2e[(size_t)c * ACH + a] = f2bf(w * s1 * LOG2E);   // logits in log2 units
            acc += w * (be1[a] - s1 * rm1[a]);
        }
        #pragma unroll
        for (int d = 1; d < 64; d <<= 1) acc += __shfl_xor(acc, d);
        if (l == 0) b2e[c] = (b2[c] + acc) * LOG2E;
    }
}

// ---------------- B2n: hbias[b][a] = b1[a] + sum_c w1m*mean + w1s*std
__global__ __launch_bounds__(64) void kB2n(const float* __restrict__ w1,
                                           const float* __restrict__ b1,
                                           const float* __restrict__ st1,
                                           const float* __restrict__ st2,
                                           float* __restrict__ hbias) {
    int a = blockIdx.x, b = blockIdx.y, l = threadIdx.x;
    const float* wr = w1 + (size_t)a * 3 * CCH;
    const float* p1 = st1 + (size_t)b * CCH;
    const float* p2 = st2 + (size_t)b * CCH;
    const size_t half = (size_t)BATCH * CCH;
    float acc = 0.f;
    const float invT = 1.f / (float)TLEN;
    const float invT1 = 1.f / (float)(TLEN - 1);
    for (int k = l; k < CCH; k += 64) {
        float s1 = p1[k] + p1[half + k];
        float s2 = p2[k] + p2[half + k];
        float mean = s1 * invT;
        float var = (s2 - s1 * s1 * invT) * invT1;
        float stdv = sqrtf(var + EPSV);
        acc += wr[CCH + k] * mean + wr[2 * CCH + k] * stdv;
    }
    #pragma unroll
    for (int d = 1; d < 64; d <<= 1) acc += __shfl_xor(acc, d);
    if (l == 0) hbias[b * ACH + a] = acc + b1[a];
}

// ---------------- C3: GEMM1 h[b][t][a] = relu(w1x @ xt^T + hbias), LDS-staged MFMA
__global__ __launch_bounds__(512) void kC3(const unsigned short* __restrict__ xt,
                                           const unsigned short* __restrict__ w1x,
                                           const float* __restrict__ hbias,
                                           unsigned short* __restrict__ h) {
    int b = blockIdx.y;
    int t0 = blockIdx.x * 64;
    int tid = threadIdx.x;
    int wv = tid >> 6, l = tid & 63, g = l >> 4, r = l & 15;
    int a0 = (wv & 3) * 32;
    int tw = (wv >> 2) * 32;

    __shared__ uint4 As[2][1024];   // [128a][64c] bf16, swizzled 16B chunks (8/row)
    __shared__ uint4 Bs[2][512];    // [64t][64c]  bf16, swizzled

    const unsigned short* bG = xt + (size_t)b * NCB * XTB;   // panel base for batch b

    int qa0 = tid, qa1 = tid + 512, qb = tid;
    int wa0 = qa0 ^ ((qa0 >> 3) & 7), wa1 = qa1 ^ ((qa1 >> 3) & 7), wb = qb ^ ((qb >> 3) & 7);
    int arow0 = qa0 >> 3, arow1 = qa1 >> 3, acol = (qa0 & 7) * 8;
    int brow = qb >> 3, bcol = (qb & 7) * 8;

    As[0][wa0] = *reinterpret_cast<const uint4*>(w1x + (size_t)arow0 * CCH + acol);
    As[0][wa1] = *reinterpret_cast<const uint4*>(w1x + (size_t)arow1 * CCH + acol);
    Bs[0][wb]  = *reinterpret_cast<const uint4*>(bG + (size_t)(t0 + brow) * 64 + bcol);
    __syncthreads();

    f32x4 acc[2][2];
    #pragma unroll
    for (int i = 0; i < 2; ++i)
        #pragma unroll
        for (int j = 0; j < 2; ++j) acc[i][j] = f32x4{0.f, 0.f, 0.f, 0.f};

    for (int ks = 0; ks < CCH / 64; ++ks) {
        int buf = ks & 1;
        uint4 na0, na1, nb;
        if (ks < CCH / 64 - 1) {
            int cofs = (ks + 1) * 64;
            na0 = *reinterpret_cast<const uint4*>(w1x + (size_t)arow0 * CCH + cofs + acol);
            na1 = *reinterpret_cast<const uint4*>(w1x + (size_t)arow1 * CCH + cofs + acol);
            nb  = *reinterpret_cast<const uint4*>(bG + (size_t)(ks + 1) * XTB + (size_t)(t0 + brow) * 64 + bcol);
        }
        bf16x8 Af[2][2], Bf[2][2];
        #pragma unroll
        for (int at = 0; at < 2; ++at) {
            int row = a0 + 16 * at + r;
            #pragma unroll
            for (int kk = 0; kk < 2; ++kk) {
                int ch = (row * 8 + kk * 4 + g) ^ (row & 7);
                Af[at][kk] = *reinterpret_cast<const bf16x8*>(&As[buf][ch]);
            }
        }
        #pragma unroll
        for (int tt = 0; tt < 2; ++tt) {
            int row = tw + 16 * tt + r;
            #pragma unroll
            for (int kk = 0; kk < 2; ++kk) {
                int ch = (row * 8 + kk * 4 + g) ^ (row & 7);
                Bf[tt][kk] = *reinterpret_cast<const bf16x8*>(&Bs[buf][ch]);
            }
        }
        #pragma unroll
        for (int kk = 0; kk < 2; ++kk)
            #pragma unroll
            for (int at = 0; at < 2; ++at)
                #pragma unroll
                for (int tt = 0; tt < 2; ++tt)
                    acc[at][tt] = __builtin_amdgcn_mfma_f32_16x16x32_bf16(Af[at][kk], Bf[tt][kk], acc[at][tt], 0, 0, 0);
        if (ks < CCH / 64 - 1) {
            As[buf ^ 1][wa0] = na0;
            As[buf ^ 1][wa1] = na1;
            Bs[buf ^ 1][wb]  = nb;
        }
        __syncthreads();
    }

    #pragma unroll
    for (int at = 0; at < 2; ++at) {
        f32x4 hb = *reinterpret_cast<const f32x4*>(hbias + b * ACH + a0 + 16 * at + 4 * g);
        #pragma unroll
        for (int tt = 0; tt < 2; ++tt) {
            int t = t0 + tw + 16 * tt + r;
            float v0 = acc[at][tt][0] + hb[0]; v0 = v0 > 0.f ? v0 : 0.f;
            float v1 = acc[at][tt][1] + hb[1]; v1 = v1 > 0.f ? v1 : 0.f;
            float v2 = acc[at][tt][2] + hb[2]; v2 = v2 > 0.f ? v2 : 0.f;
            float v3 = acc[at][tt][3] + hb[3]; v3 = v3 > 0.f ? v3 : 0.f;
            uint2 u;
            u.x = (unsigned)f2bf(v0) | ((unsigned)f2bf(v1) << 16);
            u.y = (unsigned)f2bf(v2) | ((unsigned)f2bf(v3) << 16);
            *reinterpret_cast<uint2*>(h + ((size_t)(b * TPAD + t)) * ACH + a0 + 16 * at + 4 * g) = u;
        }
    }
}

// Fallback GEMM1: gather x fp32 directly (slow but correct), used if no room for xt
__global__ __launch_bounds__(256) void kC2(const float* __restrict__ x,
                                           const unsigned short* __restrict__ w1x,
                                           const float* __restrict__ hbias,
                                           unsigned short* __restrict__ h) {
    int b = blockIdx.y;
    int t0 = blockIdx.x * 32;
    int tid = threadIdx.x;
    int wv = tid >> 6, l = tid & 63, g = l >> 4, r = l & 15;
    const unsigned short* aptr = w1x + (size_t)(32 * wv + r) * CCH + 8 * g;
    f32x4 acc[2][2];
    #pragma unroll
    for (int i = 0; i < 2; ++i)
        #pragma unroll
        for (int j = 0; j < 2; ++j) acc[i][j] = f32x4{0.f, 0.f, 0.f, 0.f};
    for (int kk = 0; kk < CCH / 32; ++kk) {
        bf16x8 Af[2], Bf[2];
        #pragma unroll
        for (int at = 0; at < 2; ++at)
            Af[at] = *reinterpret_cast<const bf16x8*>(aptr + (size_t)(16 * at) * CCH + 32 * kk);
        #pragma unroll
        for (int tt = 0; tt < 2; ++tt) {
            int t = t0 + 16 * tt + r;
            unsigned short tmp[8];
            #pragma unroll
            for (int j = 0; j < 8; ++j) {
                float xv = 0.f;
                if (t < TLEN) xv = x[((size_t)(b * CCH + 32 * kk + 8 * g + j)) * TLEN + t];
                tmp[j] = f2bf(xv);
            }
            Bf[tt] = *reinterpret_cast<const bf16x8*>(tmp);
        }
        #pragma unroll
        for (int at = 0; at < 2; ++at)
            #pragma unroll
            for (int tt = 0; tt < 2; ++tt)
                acc[at][tt] = __builtin_amdgcn_mfma_f32_16x16x32_bf16(Af[at], Bf[tt], acc[at][tt], 0, 0, 0);
    }
    #pragma unroll
    for (int at = 0; at < 2; ++at) {
        f32x4 hb = *reinterpret_cast<const f32x4*>(hbias + b * ACH + 32 * wv + 16 * at + 4 * g);
        #pragma unroll
        for (int tt = 0; tt < 2; ++tt) {
            int t = t0 + 16 * tt + r;
            float v0 = acc[at][tt][0] + hb[0]; v0 = v0 > 0.f ? v0 : 0.f;
            float v1 = acc[at][tt][1] + hb[1]; v1 = v1 > 0.f ? v1 : 0.f;
            float v2 = acc[at][tt][2] + hb[2]; v2 = v2 > 0.f ? v2 : 0.f;
            float v3 = acc[at][tt][3] + hb[3]; v3 = v3 > 0.f ? v3 : 0.f;
            uint2 u;
            u.x = (unsigned)f2bf(v0) | ((unsigned)f2bf(v1) << 16);
            u.y = (unsigned)f2bf(v2) | ((unsigned)f2bf(v3) << 16);
            *reinterpret_cast<uint2*>(h + ((size_t)(b * TPAD + t)) * ACH + 32 * wv + 16 * at + 4 * g) = u;
        }
    }
}

// ---------------- D4: GEMM2 + online softmax partials; BOTH h and x staged through
// swizzled LDS with coalesced chunk loads (x chunk = 2 contiguous 4KB panels).
// block: 128 channels x 256 t-chunk; 4 waves; grid (CCH/128, B, TSPLIT=4)
__global__ __launch_bounds__(256) void kD4(const unsigned short* __restrict__ xt,
                                           const unsigned short* __restrict__ h,
                                           const unsigned short* __restrict__ w2e,
                                           const float* __restrict__ b2e,
                                           float4* __restrict__ part) {
    int b = blockIdx.y, ts = blockIdx.z;
    int cblk = blockIdx.x * 128;
    int tid = threadIdx.x;
    int wv = tid >> 6, l = tid & 63, g = l >> 4, r = l & 15;
    int c0 = cblk + 32 * wv;
    int t0 = ts * TCHUNK;

    __shared__ uint4 hs[2][512];    // [32t][128a] bf16, swizzled 16B chunks (16/row)
    __shared__ uint2 xs[2][1024];   // [32t][128c] bf16, swizzled 8B granules

    bf16x8 W[2][4];
    f32x4 b2v[2];
    #pragma unroll
    for (int af = 0; af < 2; ++af) {
        #pragma unroll
        for (int kk = 0; kk < 4; ++kk)
            W[af][kk] = *reinterpret_cast<const bf16x8*>(w2e + (size_t)(c0 + 16 * af + r) * ACH + 32 * kk + 8 * g);
        b2v[af] = *reinterpret_cast<const f32x4*>(b2e + c0 + 16 * af + 4 * g);
    }

    const unsigned short* hbase = h + (size_t)(b * TPAD + t0) * ACH;
    const unsigned short* xpan = xt + ((size_t)b * NCB + (cblk >> 6)) * XTB;  // 2 panels

    // h staging indices
    int q0 = tid, q1 = tid + 256;
    int w0 = q0 ^ ((q0 >> 4) & 7), w1 = q1 ^ ((q1 >> 4) & 7);
    // x staging indices: thread covers (t=tid>>3, c8=tid&7) in panel 0 and panel 1
    int xtl = tid >> 3, xw7 = tid & 7;
    int xc0 = (xtl * 16 + xw7) ^ (xtl & 7);        // panel 0 chunk
    int xc1 = (xtl * 16 + 8 + xw7) ^ (xtl & 7);    // panel 1 chunk
    // x read granule indices (uint2): element (t,c): granule (t*32 + (c>>2)) ^ ((t&7)<<1)
    int xg[2];
    #pragma unroll
    for (int af = 0; af < 2; ++af) {
        int gx = 8 * wv + 4 * af + g;              // c_local>>2
        xg[af] = (r * 32 + gx) ^ ((r & 7) << 1);   // t_local = r; +512 for r+16
    }

    auto ldH = [&](int tc, uint4& a, uint4& bq) {
        const unsigned short* src = hbase + (size_t)tc * 32 * ACH;
        a  = *reinterpret_cast<const uint4*>(src + q0 * 8);
        bq = *reinterpret_cast<const uint4*>(src + q1 * 8);
    };
    auto ldX = [&](int tc, uint4& a, uint4& bq) {
        size_t off = (size_t)(t0 + tc * 32 + xtl) * 64 + xw7 * 8;
        a  = *reinterpret_cast<const uint4*>(xpan + off);
        bq = *reinterpret_cast<const uint4*>(xpan + XTB + off);
    };

    {
        uint4 h0, h1, x0, x1;
        ldH(0, h0, h1); ldX(0, x0, x1);
        hs[0][w0] = h0; hs[0][w1] = h1;
        *reinterpret_cast<uint4*>(&xs[0][2 * xc0]) = x0;
        *reinterpret_cast<uint4*>(&xs[0][2 * xc1]) = x1;
    }
    __syncthreads();

    float m[2][4], s[2][4], wx[2][4], wxx[2][4];
    #pragma unroll
    for (int af = 0; af < 2; ++af)
        #pragma unroll
        for (int i = 0; i < 4; ++i) { m[af][i] = NINF; s[af][i] = 0.f; wx[af][i] = 0.f; wxx[af][i] = 0.f; }

    for (int tc = 0; tc < TCHUNK / 32; ++tc) {
        int buf = tc & 1;
        uint4 nh0, nh1, nx0, nx1;
        if (tc < TCHUNK / 32 - 1) {
            ldH(tc + 1, nh0, nh1);
            ldX(tc + 1, nx0, nx1);
        }

        f32x4 a2[2][2];
        a2[0][0] = f32x4{0.f, 0.f, 0.f, 0.f}; a2[0][1] = f32x4{0.f, 0.f, 0.f, 0.f};
        a2[1][0] = f32x4{0.f, 0.f, 0.f, 0.f}; a2[1][1] = f32x4{0.f, 0.f, 0.f, 0.f};
        #pragma unroll
        for (int tt = 0; tt < 2; ++tt) {
            int tl = tt * 16 + r;
            #pragma unroll
            for (int kk = 0; kk < 4; ++kk) {
                int ch = (tl * 16 + kk * 4 + g) ^ (tl & 7);
                bf16x8 Bf = *reinterpret_cast<const bf16x8*>(&hs[buf][ch]);
                a2[0][tt] = __builtin_amdgcn_mfma_f32_16x16x32_bf16(W[0][kk], Bf, a2[0][tt], 0, 0, 0);
                a2[1][tt] = __builtin_amdgcn_mfma_f32_16x16x32_bf16(W[1][kk], Bf, a2[1][tt], 0, 0, 0);
            }
        }

        int tb0 = t0 + tc * 32 + r, tb1 = tb0 + 16;
        bool val0 = (tb0 < TLEN), val1 = (tb1 < TLEN);
        #pragma unroll
        for (int af = 0; af < 2; ++af) {
            uint2 xu0 = xs[buf][xg[af]];
            uint2 xu1 = xs[buf][xg[af] + 512];
            float xv0[4], xv1[4];
            xv0[0] = bf2f((unsigned short)(xu0.x & 0xffff));
            xv0[1] = bf2f((unsigned short)(xu0.x >> 16));
            xv0[2] = bf2f((unsigned short)(xu0.y & 0xffff));
            xv0[3] = bf2f((unsigned short)(xu0.y >> 16));
            xv1[0] = bf2f((unsigned short)(xu1.x & 0xffff));
            xv1[1] = bf2f((unsigned short)(xu1.x >> 16));
            xv1[2] = bf2f((unsigned short)(xu1.y & 0xffff));
            xv1[3] = bf2f((unsigned short)(xu1.y >> 16));
            #pragma unroll
            for (int i = 0; i < 4; ++i) {
                float v0 = val0 ? (a2[af][0][i] + b2v[af][i]) : NINF;
                float v1 = val1 ? (a2[af][1][i] + b2v[af][i]) : NINF;
                float mx = fmaxf(v0, v1);
                if (__any(mx > m[af][i] + RTHR)) {   // wave-uniform deferred rescale (T13)
                    float mn = fmaxf(m[af][i], mx);
                    float sc = exp2f(m[af][i] - mn);
                    s[af][i] *= sc; wx[af][i] *= sc; wxx[af][i] *= sc; m[af][i] = mn;
                }
                float e0 = exp2f(v0 - m[af][i]);
                float e1 = exp2f(v1 - m[af][i]);
                float xe0 = xv0[i] * e0, xe1 = xv1[i] * e1;
                s[af][i]   += e0 + e1;
                wx[af][i]  += xe0 + xe1;
                wxx[af][i] += xv0[i] * xe0 + xv1[i] * xe1;
            }
        }

        if (tc < TCHUNK / 32 - 1) {
            hs[buf ^ 1][w0] = nh0;
            hs[buf ^ 1][w1] = nh1;
            *reinterpret_cast<uint4*>(&xs[buf ^ 1][2 * xc0]) = nx0;
            *reinterpret_cast<uint4*>(&xs[buf ^ 1][2 * xc1]) = nx1;
        }
        __syncthreads();
    }

    // merge across the 16 lanes (r) that share each channel
    #pragma unroll
    for (int af = 0; af < 2; ++af)
        #pragma unroll
        for (int i = 0; i < 4; ++i) {
            float mm = m[af][i], ss = s[af][i], sx = wx[af][i], sxx = wxx[af][i];
            #pragma unroll
            for (int d = 1; d < 16; d <<= 1) {
                float mo = __shfl_xor(mm, d);
                float so = __shfl_xor(ss, d);
                float xo = __shfl_xor(sx, d);
                float qo = __shfl_xor(sxx, d);
                float mn = fmaxf(mm, mo);
                float fa = exp2f(mm - mn), fb = exp2f(mo - mn);
                ss = ss * fa + so * fb;
                sx = sx * fa + xo * fb;
                sxx = sxx * fa + qo * fb;
                mm = mn;
            }
            if (r == 0) {
                int c = c0 + 16 * af + 4 * g + i;
                float4 p; p.x = mm; p.y = ss; p.z = sx; p.w = sxx;
                part[((size_t)(b * TSPLIT + ts)) * CCH + c] = p;
            }
        }
}

// Fallback D (reads fp32 x via LDS staging) — used only when xt doesn't fit
__global__ __launch_bounds__(256) void kD1(const float* __restrict__ x,
                                           const unsigned short* __restrict__ h,
                                           const unsigned short* __restrict__ w2e,
                                           const float* __restrict__ b2e,
                                           float4* __restrict__ part) {
    int b = blockIdx.y, ts = blockIdx.z;
    int cblk = blockIdx.x * 64;
    int tid = threadIdx.x;
    int wv = tid >> 6, l = tid & 63, g = l >> 4, r = l & 15;
    int c0 = cblk + 16 * wv;
    int t0 = ts * TCHUNK;
    __shared__ float xsf[2][64][36];

    bf16x8 W[4];
    #pragma unroll
    for (int kk = 0; kk < 4; ++kk)
        W[kk] = *reinterpret_cast<const bf16x8*>(w2e + (size_t)(c0 + r) * ACH + 32 * kk + 8 * g);
    f32x4 b2v = *reinterpret_cast<const f32x4*>(b2e + c0 + 4 * g);

    int sc_ = tid >> 2;
    int st_ = (tid & 3) * 8;
    const float* xrow = x + ((size_t)(b * CCH + cblk + sc_)) * TLEN;
    const unsigned short* hb = h + (size_t)(b * TPAD) * ACH + 8 * g;

    auto stage = [&](int buf, int tc) {
        int tg = t0 + tc * 32;
        #pragma unroll
        for (int p = 0; p < 2; ++p) {
            int tl = st_ + 4 * p;
            float4 v = make_float4(0.f, 0.f, 0.f, 0.f);
            if (tg + tl < TLEN) v = *reinterpret_cast<const float4*>(xrow + tg + tl);
            *reinterpret_cast<float4*>(&xsf[buf][sc_][tl]) = v;
        }
    };

    float m[4], s[4], wx[4], wxx[4];
    #pragma unroll
    for (int i = 0; i < 4; ++i) { m[i] = NINF; s[i] = 0.f; wx[i] = 0.f; wxx[i] = 0.f; }

    stage(0, 0);
    __syncthreads();
    for (int tc = 0; tc < TCHUNK / 32; ++tc) {
        int buf = tc & 1;
        if (tc + 1 < TCHUNK / 32) stage(buf ^ 1, tc + 1);
        f32x4 a2[2];
        a2[0] = f32x4{0.f, 0.f, 0.f, 0.f};
        a2[1] = f32x4{0.f, 0.f, 0.f, 0.f};
        #pragma unroll
        for (int tt = 0; tt < 2; ++tt) {
            int t = t0 + tc * 32 + tt * 16 + r;
            #pragma unroll
            for (int kk = 0; kk < 4; ++kk) {
                bf16x8 Bf = *reinterpret_cast<const bf16x8*>(hb + (size_t)t * ACH + 32 * kk);
                a2[tt] = __builtin_amdgcn_mfma_f32_16x16x32_bf16(W[kk], Bf, a2[tt], 0, 0, 0);
            }
        }
        int tb = t0 + tc * 32 + r;
        bool val0 = (tb < TLEN), val1 = (tb + 16 < TLEN);
        #pragma unroll
        for (int i = 0; i < 4; ++i) {
            int cl = 16 * wv + 4 * g + i;
            float v0 = val0 ? (a2[0][i] + b2v[i]) : NINF;
            float v1 = val1 ? (a2[1][i] + b2v[i]) : NINF;
            float mx = fmaxf(v0, v1);
            if (mx > m[i] + RTHR) {
                float sc = exp2f(m[i] - mx);
                s[i] *= sc; wx[i] *= sc; wxx[i] *= sc; m[i] = mx;
            }
            float e0 = exp2f(v0 - m[i]);
            float e1 = exp2f(v1 - m[i]);
            float x0 = xsf[buf][cl][r];
            float x1 = xsf[buf][cl][r + 16];
            float xe0 = x0 * e0, xe1 = x1 * e1;
            s[i]   += e0 + e1;
            wx[i]  += xe0 + xe1;
            wxx[i] += x0 * xe0 + x1 * xe1;
        }
        __syncthreads();
    }

    #pragma unroll
    for (int i = 0; i < 4; ++i) {
        float mm = m[i], ss = s[i], sx = wx[i], sxx = wxx[i];
        #pragma unroll
        for (int d = 1; d < 16; d <<= 1) {
            float mo = __shfl_xor(mm, d);
            float so = __shfl_xor(ss, d);
            float xo = __shfl_xor(sx, d);
            float qo = __shfl_xor(sxx, d);
            float mn = fmaxf(mm, mo);
            float fa = exp2f(mm - mn), fb = exp2f(mo - mn);
            ss = ss * fa + so * fb;
            sx = sx * fa + xo * fb;
            sxx = sxx * fa + qo * fb;
            mm = mn;
        }
        if (r == 0) {
            int c = c0 + 4 * g + i;
            float4 p; p.x = mm; p.y = ss; p.z = sx; p.w = sxx;
            part[((size_t)(b * TSPLIT + ts)) * CCH + c] = p;
        }
    }
}

// ---------------- E: merge T-chunk partials + BN2
__global__ __launch_bounds__(256) void kE(const float4* __restrict__ part,
                                          const float* __restrict__ rm2,
                                          const float* __restrict__ rv2,
                                          const float* __restrict__ g2,
                                          const float* __restrict__ be2,
                                          float* __restrict__ out) {
    int idx = blockIdx.x * 256 + threadIdx.x;   // < BATCH*CCH
    int b = idx / CCH, c = idx - b * CCH;
    float m = NINF, s = 0.f, wx = 0.f, wxx = 0.f;
    #pragma unroll
    for (int ts = 0; ts < TSPLIT; ++ts) {
        float4 p = part[((size_t)(b * TSPLIT + ts)) * CCH + c];
        float mn = fmaxf(m, p.x);
        float fa = exp2f(m - mn), fb = exp2f(p.x - mn);
        s = s * fa + p.y * fb;
        wx = wx * fa + p.z * fb;
        wxx = wxx * fa + p.w * fb;
        m = mn;
    }
    float mu = wx / s;
    float ssq = wxx / s;
    float sig = sqrtf(fabsf(ssq - mu * mu) + EPSV);
    out[b * 2 * CCH + c] = (mu - rm2[c]) * g2[c] * rsqrtf(rv2[c] + EPSV) + be2[c];
    int c2 = CCH + c;
    out[b * 2 * CCH + c2] = (sig - rm2[c2]) * g2[c2] * rsqrtf(rv2[c2] + EPSV) + be2[c2];
}

extern "C" void kernel_launch(void* const* d_in, const int* in_sizes, int n_in,
                              void* d_out, int out_size, void* d_ws, size_t ws_size,
                              hipStream_t stream) {
    const float* x   = (const float*)d_in[0];
    const float* w1  = (const float*)d_in[1];
    const float* b1  = (const float*)d_in[2];
    const float* g1  = (const float*)d_in[3];
    const float* be1 = (const float*)d_in[4];
    const float* rm1 = (const float*)d_in[5];
    const float* rv1 = (const float*)d_in[6];
    const float* w2  = (const float*)d_in[7];
    const float* b2  = (const float*)d_in[8];
    const float* g2  = (const float*)d_in[9];
    const float* be2 = (const float*)d_in[10];
    const float* rm2 = (const float*)d_in[11];
    const float* rv2 = (const float*)d_in[12];
    float* out = (float*)d_out;

    const size_t sz_xt    = (size_t)BATCH * NCB * XTB * 2;    // 100.7 MB (blocked layout)
    const size_t sz_h     = (size_t)BATCH * TPAD * ACH * 2;   // 8.4 MB
    const size_t sz_w1x   = (size_t)ACH * CCH * 2;
    const size_t sz_w2e   = (size_t)CCH * ACH * 2;
    const size_t sz_st    = (size_t)TSA * BATCH * CCH * 4;    // stat partials (x2)
    const size_t sz_hbias = (size_t)BATCH * ACH * 4;
    const size_t sz_b2e   = (size_t)CCH * 4;
    const size_t sz_part  = (size_t)BATCH * TSPLIT * CCH * 16; // 3.1 MB
    const size_t need_small = sz_h + sz_w1x + sz_w2e + 2 * sz_st
                            + sz_hbias + sz_b2e + sz_part;
    bool use_xt = (ws_size >= need_small + sz_xt);

    char* ws = (char*)d_ws;
    unsigned short* xt = nullptr;
    if (use_xt) { xt = (unsigned short*)ws; ws += sz_xt; }
    unsigned short* hbuf = (unsigned short*)ws; ws += sz_h;
    unsigned short* w1x  = (unsigned short*)ws; ws += sz_w1x;
    unsigned short* w2e  = (unsigned short*)ws; ws += sz_w2e;
    float* st1   = (float*)ws; ws += sz_st;
    float* st2   = (float*)ws; ws += sz_st;
    float* hbias = (float*)ws; ws += sz_hbias;
    float* b2e   = (float*)ws; ws += sz_b2e;
    float4* part = (float4*)ws; ws += sz_part;

    const int NBW = (ACH * CCH) / 256 + CCH / 4;   // 768 + 384
    if (use_xt)
        kA<<<dim3(NCB, BATCH, TSA), 512, 0, stream>>>(x, xt, st1, st2);
    else
        kA2<<<dim3(48, 32), 256, 0, stream>>>(x, st1, st2);
    kBW<<<NBW, 256, 0, stream>>>(w1, w1x, w2, b2, g1, be1, rm1, rv1, w2e, b2e);
    kB2n<<<dim3(ACH, BATCH), 64, 0, stream>>>(w1, b1, st1, st2, hbias);
    if (use_xt) {
        kC3<<<dim3(TPAD / 64, BATCH), 512, 0, stream>>>(xt, w1x, hbias, hbuf);
        kD4<<<dim3(CCH / 128, BATCH, TSPLIT), 256, 0, stream>>>(xt, hbuf, w2e, b2e, part);
    } else {
        kC2<<<dim3(TPAD / 32, BATCH), 256, 0, stream>>>(x, w1x, hbias, hbuf);
        kD1<<<dim3(CCH / 64, BATCH, TSPLIT), 256, 0, stream>>>(x, hbuf, w2e, b2e, part);
    }
    kE<<<(BATCH * CCH) / 256, 256, 0, stream>>>(part, rm2, rv2, g2, be2, out);
}